// Round 1
// baseline (826.542 us; speedup 1.0000x reference)
//
#include <hip/hip_runtime.h>
#include <math.h>

// Problem constants (reference: B,P,D,N,K = 8,784,1536,20000,9)
#define B_    8
#define P_    784
#define M_    6272      // B*P
#define D_    1536
#define N_    20000
#define NPAD_ 20096     // 157*128
#define NT_   157       // N tiles of 128
#define MT_   49        // M tiles of 128
#define KS_   48        // 1536/32 K-steps
#define NC_   4         // candidate patches per image

using bf16x8 = __attribute__((ext_vector_type(8))) __bf16;
using f32x4v = __attribute__((ext_vector_type(4))) float;

#define GLD_LDS16(src, dst)                                            \
  __builtin_amdgcn_global_load_lds(                                    \
      (__attribute__((address_space(1))) const void*)(src),            \
      (__attribute__((address_space(3))) void*)(dst), 16, 0, 0)

__device__ __forceinline__ unsigned short f2bf(float f) {
  union { float f; unsigned u; } v; v.f = f;
  unsigned r = v.u + 0x7fffu + ((v.u >> 16) & 1u);
  return (unsigned short)(r >> 16);
}

// ---------------- K0/K1: fp32 -> bf16 rows + row sum-of-squares ----------------
// grid = nrows blocks of 256 threads; rows >= realrows are zero-padded, sq=1e30
__global__ void convert_rows(const float* __restrict__ src,
                             unsigned short* __restrict__ dst,
                             float* __restrict__ sq, int realrows) {
  const int row = blockIdx.x;
  const int t = threadIdx.x;
  if (row >= realrows) {
    for (int i = t; i < D_; i += 256) dst[(size_t)row * D_ + i] = 0;
    if (t == 0) sq[row] = 1e30f;
    return;
  }
  const float* r = src + (size_t)row * D_;
  unsigned short* w = dst + (size_t)row * D_;
  float s = 0.f;
#pragma unroll
  for (int j = 0; j < D_ / 256; ++j) {
    int i = j * 256 + t;
    float v = r[i];
    s += v * v;
    w[i] = f2bf(v);
  }
#pragma unroll
  for (int m = 32; m >= 1; m >>= 1) s += __shfl_xor(s, m);
  __shared__ float ws4[4];
  if ((t & 63) == 0) ws4[t >> 6] = s;
  __syncthreads();
  if (t == 0) sq[row] = ws4[0] + ws4[1] + ws4[2] + ws4[3];
}

// ---------------- K2: bf16 MFMA GEMM with fused row-min epilogue ----------------
// partial[nTile][row] = min over this tile's 128 cols of (m2[c] - 2*x.m_c)
__global__ __launch_bounds__(256) void gemm_min_kernel(
    const unsigned short* __restrict__ xbf, const unsigned short* __restrict__ mbf,
    const float* __restrict__ m2, float* __restrict__ partial) {
  __shared__ unsigned short ldsA[128 * 32];  // 8 KB, row-major [128][32]
  __shared__ unsigned short ldsB[128 * 32];  // 8 KB
  __shared__ float ldsMin[2][128];

  const int tid = threadIdx.x;
  const int lane = tid & 63, wid = tid >> 6;
  const int wm = wid >> 1, wn = wid & 1;
  const int nTile = blockIdx.x, mTile = blockIdx.y;
  const int mBase = mTile * 128, nBase = nTile * 128;

  f32x4v acc[4][4];
#pragma unroll
  for (int i = 0; i < 4; ++i)
#pragma unroll
    for (int j = 0; j < 4; ++j) acc[i][j] = f32x4v{0.f, 0.f, 0.f, 0.f};

  // staging: 8 chunks of 1KB per tile; wave w stages chunks {2w, 2w+1} of A and B
  const int c0 = wid * 2, c1 = wid * 2 + 1;
  const size_t aoff0 = (size_t)(mBase + c0 * 16 + (lane >> 2)) * D_ + (lane & 3) * 8;
  const size_t aoff1 = (size_t)(mBase + c1 * 16 + (lane >> 2)) * D_ + (lane & 3) * 8;
  const size_t boff0 = (size_t)(nBase + c0 * 16 + (lane >> 2)) * D_ + (lane & 3) * 8;
  const size_t boff1 = (size_t)(nBase + c1 * 16 + (lane >> 2)) * D_ + (lane & 3) * 8;

  const int g = lane >> 4, r16 = lane & 15;
  const int aRdBase = (wm * 64 + r16) * 32 + g * 8;  // + mf*16*32
  const int bRdBase = (wn * 64 + r16) * 32 + g * 8;

  for (int ks = 0; ks < KS_; ++ks) {
    __syncthreads();  // previous compute done reading LDS
    const int ko = ks * 32;
    GLD_LDS16(xbf + aoff0 + ko, &ldsA[c0 * 512]);
    GLD_LDS16(xbf + aoff1 + ko, &ldsA[c1 * 512]);
    GLD_LDS16(mbf + boff0 + ko, &ldsB[c0 * 512]);
    GLD_LDS16(mbf + boff1 + ko, &ldsB[c1 * 512]);
    __syncthreads();  // vmcnt drained before barrier -> tiles visible

    bf16x8 av[4], bv[4];
#pragma unroll
    for (int mf = 0; mf < 4; ++mf)
      av[mf] = *(const bf16x8*)&ldsA[aRdBase + mf * 16 * 32];
#pragma unroll
    for (int nf = 0; nf < 4; ++nf)
      bv[nf] = *(const bf16x8*)&ldsB[bRdBase + nf * 16 * 32];
#pragma unroll
    for (int mf = 0; mf < 4; ++mf)
#pragma unroll
      for (int nf = 0; nf < 4; ++nf)
        acc[mf][nf] = __builtin_amdgcn_mfma_f32_16x16x32_bf16(av[mf], bv[nf], acc[mf][nf], 0, 0, 0);
  }

  // epilogue: per-row min over the 128 cols.
  // C/D layout (m89-verified): col = lane&15, row = (lane>>4)*4 + reg
  float m2v[4];
#pragma unroll
  for (int nf = 0; nf < 4; ++nf) m2v[nf] = m2[nBase + wn * 64 + nf * 16 + r16];
#pragma unroll
  for (int mf = 0; mf < 4; ++mf) {
    float mn[4];
#pragma unroll
    for (int i = 0; i < 4; ++i) {
      float v = m2v[0] - 2.f * acc[mf][0][i];
      v = fminf(v, m2v[1] - 2.f * acc[mf][1][i]);
      v = fminf(v, m2v[2] - 2.f * acc[mf][2][i]);
      v = fminf(v, m2v[3] - 2.f * acc[mf][3][i]);
      mn[i] = v;
    }
#pragma unroll
    for (int msk = 1; msk < 16; msk <<= 1)
#pragma unroll
      for (int i = 0; i < 4; ++i) mn[i] = fminf(mn[i], __shfl_xor(mn[i], msk));
    if (r16 == 0)
#pragma unroll
      for (int i = 0; i < 4; ++i)
        ldsMin[wn][wm * 64 + mf * 16 + g * 4 + i] = mn[i];
  }
  __syncthreads();
  if (tid < 128)
    partial[(size_t)nTile * M_ + mBase + tid] = fminf(ldsMin[0][tid], ldsMin[1][tid]);
}

// ---------------- K3: closest[row] = x2[row] + min over tiles ----------------
__global__ void reduce_min_kernel(const float* __restrict__ partial,
                                  const float* __restrict__ x2,
                                  float* __restrict__ closest) {
  const int row = blockIdx.x * 256 + threadIdx.x;
  if (row >= M_) return;
  float v = 3e38f;
  for (int t = 0; t < NT_; ++t) v = fminf(v, partial[(size_t)t * M_ + row]);
  closest[row] = x2[row] + v;
}

// ---------------- K4: per image, top-NC patches by (approx) closest, desc ----------------
__global__ void topcand_kernel(const float* __restrict__ closest, int* __restrict__ cand) {
  const int b = blockIdx.x;
  __shared__ float ls[P_];
  for (int i = threadIdx.x; i < P_; i += 256) ls[i] = closest[b * P_ + i];
  __syncthreads();
  if (threadIdx.x == 0) {
    float bv[NC_]; int bi[NC_];
    for (int c = 0; c < NC_; ++c) { bv[c] = -3e38f; bi[c] = 0; }
    for (int p = 0; p < P_; ++p) {
      float v = ls[p];
      if (v > bv[NC_ - 1]) {
        int q = NC_ - 1;
        while (q > 0 && bv[q - 1] < v) { bv[q] = bv[q - 1]; bi[q] = bi[q - 1]; --q; }
        bv[q] = v; bi[q] = p;
      }
    }
    for (int c = 0; c < NC_; ++c) cand[b * NC_ + c] = bi[c];
  }
}

// ---------------- K6: exact fp32 distances for the 4 candidate patches of each image ----------------
__device__ __forceinline__ float d2acc(float4 a, float4 m) {
  float dx = a.x - m.x, dy = a.y - m.y, dz = a.z - m.z, dw = a.w - m.w;
  return dx * dx + dy * dy + dz * dz + dw * dw;
}
__global__ void cand_dist_kernel(const float* __restrict__ x, const float* __restrict__ mem,
                                 const int* __restrict__ cand, float* __restrict__ dist) {
  const int b = blockIdx.y;
  const int wid = threadIdx.x >> 6, lane = threadIdx.x & 63;
  const float4* xp0 = (const float4*)(x + ((size_t)b * P_ + cand[b * NC_ + 0]) * D_);
  const float4* xp1 = (const float4*)(x + ((size_t)b * P_ + cand[b * NC_ + 1]) * D_);
  const float4* xp2 = (const float4*)(x + ((size_t)b * P_ + cand[b * NC_ + 2]) * D_);
  const float4* xp3 = (const float4*)(x + ((size_t)b * P_ + cand[b * NC_ + 3]) * D_);
  const int row0 = blockIdx.x * 32 + wid * 8;
  for (int rr = 0; rr < 8; ++rr) {
    const int row = row0 + rr;
    const float4* mrow = (const float4*)(mem + (size_t)row * D_);
    float s0 = 0.f, s1 = 0.f, s2 = 0.f, s3 = 0.f;
#pragma unroll
    for (int j = 0; j < D_ / 256; ++j) {
      float4 m4 = mrow[j * 64 + lane];
      s0 += d2acc(xp0[j * 64 + lane], m4);
      s1 += d2acc(xp1[j * 64 + lane], m4);
      s2 += d2acc(xp2[j * 64 + lane], m4);
      s3 += d2acc(xp3[j * 64 + lane], m4);
    }
#pragma unroll
    for (int msk = 32; msk >= 1; msk >>= 1) {
      s0 += __shfl_xor(s0, msk); s1 += __shfl_xor(s1, msk);
      s2 += __shfl_xor(s2, msk); s3 += __shfl_xor(s3, msk);
    }
    if (lane == 0) {
      dist[((size_t)b * NC_ + 0) * N_ + row] = s0;
      dist[((size_t)b * NC_ + 1) * N_ + row] = s1;
      dist[((size_t)b * NC_ + 2) * N_ + row] = s2;
      dist[((size_t)b * NC_ + 3) * N_ + row] = s3;
    }
  }
}

// ---------------- K7: exact top-9 (ascending) per candidate ----------------
__device__ __forceinline__ void ins9(float* t, float v) {
  if (v < t[8]) {
    int p = 8;
    while (p > 0 && t[p - 1] > v) { t[p] = t[p - 1]; --p; }
    t[p] = v;
  }
}
__global__ void top9_kernel(const float* __restrict__ dist, float* __restrict__ top9) {
  const int bc = blockIdx.x;  // 0..31
  const float* d = dist + (size_t)bc * N_;
  float t[9];
#pragma unroll
  for (int i = 0; i < 9; ++i) t[i] = 3e38f;
  for (int n = threadIdx.x; n < N_; n += 256) ins9(t, d[n]);
  __shared__ float l9[256 * 9];
  __shared__ float l9b[32 * 9];
  for (int i = 0; i < 9; ++i) l9[threadIdx.x * 9 + i] = t[i];
  __syncthreads();
  if (threadIdx.x < 32) {
    float u[9];
#pragma unroll
    for (int i = 0; i < 9; ++i) u[i] = 3e38f;
    for (int s = 0; s < 8; ++s)
      for (int i = 0; i < 9; ++i) ins9(u, l9[(threadIdx.x * 8 + s) * 9 + i]);
    for (int i = 0; i < 9; ++i) l9b[threadIdx.x * 9 + i] = u[i];
  }
  __syncthreads();
  if (threadIdx.x == 0) {
    float u[9];
#pragma unroll
    for (int i = 0; i < 9; ++i) u[i] = 3e38f;
    for (int s = 0; s < 32; ++s)
      for (int i = 0; i < 9; ++i) ins9(u, l9b[s * 9 + i]);
    for (int i = 0; i < 9; ++i) top9[bc * 9 + i] = u[i];
  }
}

// ---------------- K8: pick exact argmax candidate, compute score ----------------
__global__ void score_kernel(const float* __restrict__ top9, const int* __restrict__ cand,
                             float* __restrict__ out) {
  const int b = threadIdx.x;
  if (b >= B_) return;
  float bestv = -3e38f; int bestc = 0, bestp = 1 << 30;
  for (int c = 0; c < NC_; ++c) {
    float v = top9[(b * NC_ + c) * 9 + 0];  // exact closest of candidate patch
    int p = cand[b * NC_ + c];
    if (v > bestv || (v == bestv && p < bestp)) { bestv = v; bestc = c; bestp = p; }
  }
  const float* v9 = &top9[(b * NC_ + bestc) * 9];
  float mx = v9[8];  // sorted ascending
  float sum = 0.f, mxe = 0.f;
  for (int i = 0; i < 9; ++i) {
    float e = expf(v9[i] - mx);
    sum += e;
    if (e > mxe) mxe = e;
  }
  out[b] = (1.f - mxe / sum) * bestv;
}

// ---------------- launch ----------------
extern "C" void kernel_launch(void* const* d_in, const int* in_sizes, int n_in,
                              void* d_out, int out_size, void* d_ws, size_t ws_size,
                              hipStream_t stream) {
  const float* x = (const float*)d_in[0];
  const float* mem = (const float*)d_in[1];
  float* out = (float*)d_out;
  char* ws = (char*)d_ws;

  // ws layout (needs ~87.7 MB)
  unsigned short* xbf = (unsigned short*)(ws);                 // 19,267,584 B
  unsigned short* mbf = (unsigned short*)(ws + 19267584);      // 61,734,912 B
  float* x2      = (float*)(ws + 81002496);                    // 25,088 B
  float* m2      = (float*)(ws + 81027584);                    // 80,384 B
  float* partial = (float*)(ws + 81107968);                    // 3,938,816 B
  float* closest = (float*)(ws + 85046784);                    // 25,088 B
  int*   cand    = (int*)  (ws + 85071872);                    // 128 B
  float* dist    = (float*)(ws + 85072000);                    // 2,560,000 B
  float* top9    = (float*)(ws + 87632000);                    // 1,152 B

  convert_rows<<<NPAD_, 256, 0, stream>>>(mem, mbf, m2, N_);
  convert_rows<<<M_, 256, 0, stream>>>(x, xbf, x2, M_);
  gemm_min_kernel<<<dim3(NT_, MT_), 256, 0, stream>>>(xbf, mbf, m2, partial);
  reduce_min_kernel<<<(M_ + 255) / 256, 256, 0, stream>>>(partial, x2, closest);
  topcand_kernel<<<B_, 256, 0, stream>>>(closest, cand);
  cand_dist_kernel<<<dim3(N_ / 32, B_), 256, 0, stream>>>(x, mem, cand, dist);
  top9_kernel<<<B_ * NC_, 256, 0, stream>>>(dist, top9);
  score_kernel<<<1, 64, 0, stream>>>(top9, cand, out);
}

// Round 2
// 805.879 us; speedup vs baseline: 1.0256x; 1.0256x over previous
//
#include <hip/hip_runtime.h>
#include <math.h>

// Problem constants (reference: B,P,D,N,K = 8,784,1536,20000,9)
#define B_    8
#define P_    784
#define M_    6272      // B*P
#define D_    1536
#define N_    20000
#define NPAD_ 20096     // 157*128
#define NT_   157       // N tiles of 128
#define MT_   49        // M tiles of 128
#define KS_   48        // 1536/32 K-steps
#define NC_   4         // candidate patches per image

using bf16x8 = __attribute__((ext_vector_type(8))) __bf16;
using f32x4v = __attribute__((ext_vector_type(4))) float;

#define GLD_LDS16(src, dst)                                            \
  __builtin_amdgcn_global_load_lds(                                    \
      (__attribute__((address_space(1))) const void*)(src),            \
      (__attribute__((address_space(3))) void*)(dst), 16, 0, 0)

__device__ __forceinline__ unsigned short f2bf(float f) {
  union { float f; unsigned u; } v; v.f = f;
  unsigned r = v.u + 0x7fffu + ((v.u >> 16) & 1u);
  return (unsigned short)(r >> 16);
}

// ---------------- K0/K1: fp32 -> bf16 rows + row sum-of-squares (vectorized) ----------------
__global__ void convert_rows(const float* __restrict__ src,
                             unsigned short* __restrict__ dst,
                             float* __restrict__ sq, int realrows) {
  const int row = blockIdx.x;
  const int t = threadIdx.x;
  if (row >= realrows) {
    ushort4* w4 = (ushort4*)(dst + (size_t)row * D_);
    for (int i = t; i < D_ / 4; i += 256) w4[i] = ushort4{0, 0, 0, 0};
    if (t == 0) sq[row] = 1e30f;
    return;
  }
  const float4* r4 = (const float4*)(src + (size_t)row * D_);
  ushort4* w4 = (ushort4*)(dst + (size_t)row * D_);
  float s = 0.f;
  for (int i = t; i < D_ / 4; i += 256) {
    float4 v = r4[i];
    s += v.x * v.x + v.y * v.y + v.z * v.z + v.w * v.w;
    w4[i] = ushort4{f2bf(v.x), f2bf(v.y), f2bf(v.z), f2bf(v.w)};
  }
#pragma unroll
  for (int m = 32; m >= 1; m >>= 1) s += __shfl_xor(s, m);
  __shared__ float ws4[4];
  if ((t & 63) == 0) ws4[t >> 6] = s;
  __syncthreads();
  if (t == 0) sq[row] = ws4[0] + ws4[1] + ws4[2] + ws4[3];
}

// ---------------- K2: bf16 MFMA GEMM with fused row-min epilogue ----------------
// partial[nTile][row] = min over this tile's 128 cols of (m2[c] - 2*x.m_c)
// Grid: 1D NT_*MT_ with bijective XCD chunking (m204) + 8-mTile supertiles so
// 8 consecutive blocks on one XCD share a B-tile and keep 8 A-tiles (3.1MB) in L2.
__global__ __launch_bounds__(256) void gemm_min_kernel(
    const unsigned short* __restrict__ xbf, const unsigned short* __restrict__ mbf,
    const float* __restrict__ m2, float* __restrict__ partial) {
  __shared__ unsigned short ldsA[128 * 32];  // 8 KB, row-major [128][32]
  __shared__ unsigned short ldsB[128 * 32];  // 8 KB
  __shared__ float ldsMin[2][128];

  // --- block swizzle ---
  const int NWG = NT_ * MT_;              // 7693
  const int bid = blockIdx.x;
  const int q = NWG >> 3, r = NWG & 7;    // 961, 5
  const int xcd = bid & 7, loc = bid >> 3;
  const int wg = (xcd < r ? xcd * (q + 1) : r * (q + 1) + (xcd - r) * q) + loc;
  const int FT = 6 * 8 * NT_;             // 6 full supertile rows: 7536
  int mT, nT;
  if (wg < FT) {
    int s = wg / (8 * NT_);
    int r2 = wg - s * (8 * NT_);
    mT = s * 8 + (r2 & 7);
    nT = r2 >> 3;
  } else {
    mT = 48;
    nT = wg - FT;
  }

  const int tid = threadIdx.x;
  const int lane = tid & 63, wid = tid >> 6;
  const int wm = wid >> 1, wn = wid & 1;
  const int mBase = mT * 128, nBase = nT * 128;

  f32x4v acc[4][4];
#pragma unroll
  for (int i = 0; i < 4; ++i)
#pragma unroll
    for (int j = 0; j < 4; ++j) acc[i][j] = f32x4v{0.f, 0.f, 0.f, 0.f};

  // staging: 8 chunks of 1KB per tile; wave w stages chunks {2w, 2w+1} of A and B
  const int c0 = wid * 2, c1 = wid * 2 + 1;
  const size_t aoff0 = (size_t)(mBase + c0 * 16 + (lane >> 2)) * D_ + (lane & 3) * 8;
  const size_t aoff1 = (size_t)(mBase + c1 * 16 + (lane >> 2)) * D_ + (lane & 3) * 8;
  const size_t boff0 = (size_t)(nBase + c0 * 16 + (lane >> 2)) * D_ + (lane & 3) * 8;
  const size_t boff1 = (size_t)(nBase + c1 * 16 + (lane >> 2)) * D_ + (lane & 3) * 8;

  const int g = lane >> 4, r16 = lane & 15;
  const int aRdBase = (wm * 64 + r16) * 32 + g * 8;  // + mf*16*32
  const int bRdBase = (wn * 64 + r16) * 32 + g * 8;

  for (int ks = 0; ks < KS_; ++ks) {
    __syncthreads();  // previous compute done reading LDS
    const int ko = ks * 32;
    GLD_LDS16(xbf + aoff0 + ko, &ldsA[c0 * 512]);
    GLD_LDS16(xbf + aoff1 + ko, &ldsA[c1 * 512]);
    GLD_LDS16(mbf + boff0 + ko, &ldsB[c0 * 512]);
    GLD_LDS16(mbf + boff1 + ko, &ldsB[c1 * 512]);
    __syncthreads();  // vmcnt drained before barrier -> tiles visible

    bf16x8 av[4], bv[4];
#pragma unroll
    for (int mf = 0; mf < 4; ++mf)
      av[mf] = *(const bf16x8*)&ldsA[aRdBase + mf * 16 * 32];
#pragma unroll
    for (int nf = 0; nf < 4; ++nf)
      bv[nf] = *(const bf16x8*)&ldsB[bRdBase + nf * 16 * 32];
#pragma unroll
    for (int mf = 0; mf < 4; ++mf)
#pragma unroll
      for (int nf = 0; nf < 4; ++nf)
        acc[mf][nf] = __builtin_amdgcn_mfma_f32_16x16x32_bf16(av[mf], bv[nf], acc[mf][nf], 0, 0, 0);
  }

  // epilogue: per-row min over the 128 cols.
  // C/D layout (m89-verified): col = lane&15, row = (lane>>4)*4 + reg
  float m2v[4];
#pragma unroll
  for (int nf = 0; nf < 4; ++nf) m2v[nf] = m2[nBase + wn * 64 + nf * 16 + r16];
#pragma unroll
  for (int mf = 0; mf < 4; ++mf) {
    float mn[4];
#pragma unroll
    for (int i = 0; i < 4; ++i) {
      float v = m2v[0] - 2.f * acc[mf][0][i];
      v = fminf(v, m2v[1] - 2.f * acc[mf][1][i]);
      v = fminf(v, m2v[2] - 2.f * acc[mf][2][i]);
      v = fminf(v, m2v[3] - 2.f * acc[mf][3][i]);
      mn[i] = v;
    }
#pragma unroll
    for (int msk = 1; msk < 16; msk <<= 1)
#pragma unroll
      for (int i = 0; i < 4; ++i) mn[i] = fminf(mn[i], __shfl_xor(mn[i], msk));
    if (r16 == 0)
#pragma unroll
      for (int i = 0; i < 4; ++i)
        ldsMin[wn][wm * 64 + mf * 16 + g * 4 + i] = mn[i];
  }
  __syncthreads();
  if (tid < 128)
    partial[(size_t)nT * M_ + mBase + tid] = fminf(ldsMin[0][tid], ldsMin[1][tid]);
}

// ---------------- K3: closest[row] = x2[row] + min over tiles ----------------
__global__ void reduce_min_kernel(const float* __restrict__ partial,
                                  const float* __restrict__ x2,
                                  float* __restrict__ closest) {
  const int row = blockIdx.x * 256 + threadIdx.x;
  if (row >= M_) return;
  float v = 3e38f;
  for (int t = 0; t < NT_; ++t) v = fminf(v, partial[(size_t)t * M_ + row]);
  closest[row] = x2[row] + v;
}

// ---------------- K4: per image, top-NC patches by (approx) closest, desc ----------------
__global__ void topcand_kernel(const float* __restrict__ closest, int* __restrict__ cand) {
  const int b = blockIdx.x;
  __shared__ float ls[P_];
  for (int i = threadIdx.x; i < P_; i += 256) ls[i] = closest[b * P_ + i];
  __syncthreads();
  if (threadIdx.x == 0) {
    float bv[NC_]; int bi[NC_];
    for (int c = 0; c < NC_; ++c) { bv[c] = -3e38f; bi[c] = 0; }
    for (int p = 0; p < P_; ++p) {
      float v = ls[p];
      if (v > bv[NC_ - 1]) {
        int q = NC_ - 1;
        while (q > 0 && bv[q - 1] < v) { bv[q] = bv[q - 1]; bi[q] = bi[q - 1]; --q; }
        bv[q] = v; bi[q] = p;
      }
    }
    for (int c = 0; c < NC_; ++c) cand[b * NC_ + c] = bi[c];
  }
}

// ---------------- K6: exact fp32 distances — ONE pass over the memory bank ----------------
// Each wave owns 16 consecutive mem rows, held 4-at-a-time in registers; for each
// of the 32 (image,candidate) pairs compute 4 dots, then d = x2 + m2 - 2*dot
// (same formula as the reference, fp32). mem is read exactly once (122 MB).
__global__ __launch_bounds__(256) void cand_dist_kernel(
    const float* __restrict__ x, const float* __restrict__ mem,
    const float* __restrict__ x2, const float* __restrict__ m2,
    const int* __restrict__ cand, float* __restrict__ dist) {
  const int wid = threadIdx.x >> 6, lane = threadIdx.x & 63;
  const int row0 = blockIdx.x * 64 + wid * 16;
  for (int rr = 0; rr < 16; rr += 4) {
    const int rbase = row0 + rr;
    if (rbase >= N_) return;
    float4 m4[4][6];
    float m2r[4];
#pragma unroll
    for (int k = 0; k < 4; ++k) {
      const float4* mrow = (const float4*)(mem + (size_t)(rbase + k) * D_);
#pragma unroll
      for (int j = 0; j < 6; ++j) m4[k][j] = mrow[j * 64 + lane];
      m2r[k] = m2[rbase + k];
    }
    for (int bc = 0; bc < B_ * NC_; ++bc) {
      const int b = bc >> 2;
      const int p = cand[bc];
      const float4* xp = (const float4*)(x + ((size_t)b * P_ + p) * D_);
      float s0 = 0.f, s1 = 0.f, s2 = 0.f, s3 = 0.f;
#pragma unroll
      for (int j = 0; j < 6; ++j) {
        float4 a = xp[j * 64 + lane];
        s0 += a.x * m4[0][j].x + a.y * m4[0][j].y + a.z * m4[0][j].z + a.w * m4[0][j].w;
        s1 += a.x * m4[1][j].x + a.y * m4[1][j].y + a.z * m4[1][j].z + a.w * m4[1][j].w;
        s2 += a.x * m4[2][j].x + a.y * m4[2][j].y + a.z * m4[2][j].z + a.w * m4[2][j].w;
        s3 += a.x * m4[3][j].x + a.y * m4[3][j].y + a.z * m4[3][j].z + a.w * m4[3][j].w;
      }
#pragma unroll
      for (int msk = 32; msk >= 1; msk >>= 1) {
        s0 += __shfl_xor(s0, msk); s1 += __shfl_xor(s1, msk);
        s2 += __shfl_xor(s2, msk); s3 += __shfl_xor(s3, msk);
      }
      if (lane == 0) {
        const float xx = x2[b * P_ + p];
        dist[(size_t)bc * N_ + rbase + 0] = xx + m2r[0] - 2.f * s0;
        dist[(size_t)bc * N_ + rbase + 1] = xx + m2r[1] - 2.f * s1;
        dist[(size_t)bc * N_ + rbase + 2] = xx + m2r[2] - 2.f * s2;
        dist[(size_t)bc * N_ + rbase + 3] = xx + m2r[3] - 2.f * s3;
      }
    }
  }
}

// ---------------- K7: exact top-9 (ascending) per candidate ----------------
__device__ __forceinline__ void ins9(float* t, float v) {
  if (v < t[8]) {
    int p = 8;
    while (p > 0 && t[p - 1] > v) { t[p] = t[p - 1]; --p; }
    t[p] = v;
  }
}
__global__ void top9_kernel(const float* __restrict__ dist, float* __restrict__ top9) {
  const int bc = blockIdx.x;  // 0..31
  const float* d = dist + (size_t)bc * N_;
  float t[9];
#pragma unroll
  for (int i = 0; i < 9; ++i) t[i] = 3e38f;
  for (int n = threadIdx.x; n < N_; n += 256) ins9(t, d[n]);
  __shared__ float l9[256 * 9];
  __shared__ float l9b[32 * 9];
  for (int i = 0; i < 9; ++i) l9[threadIdx.x * 9 + i] = t[i];
  __syncthreads();
  if (threadIdx.x < 32) {
    float u[9];
#pragma unroll
    for (int i = 0; i < 9; ++i) u[i] = 3e38f;
    for (int s = 0; s < 8; ++s)
      for (int i = 0; i < 9; ++i) ins9(u, l9[(threadIdx.x * 8 + s) * 9 + i]);
    for (int i = 0; i < 9; ++i) l9b[threadIdx.x * 9 + i] = u[i];
  }
  __syncthreads();
  if (threadIdx.x == 0) {
    float u[9];
#pragma unroll
    for (int i = 0; i < 9; ++i) u[i] = 3e38f;
    for (int s = 0; s < 32; ++s)
      for (int i = 0; i < 9; ++i) ins9(u, l9b[s * 9 + i]);
    for (int i = 0; i < 9; ++i) top9[bc * 9 + i] = u[i];
  }
}

// ---------------- K8: pick exact argmax candidate, compute score ----------------
__global__ void score_kernel(const float* __restrict__ top9, const int* __restrict__ cand,
                             float* __restrict__ out) {
  const int b = threadIdx.x;
  if (b >= B_) return;
  float bestv = -3e38f; int bestc = 0, bestp = 1 << 30;
  for (int c = 0; c < NC_; ++c) {
    float v = top9[(b * NC_ + c) * 9 + 0];  // exact closest of candidate patch
    int p = cand[b * NC_ + c];
    if (v > bestv || (v == bestv && p < bestp)) { bestv = v; bestc = c; bestp = p; }
  }
  const float* v9 = &top9[(b * NC_ + bestc) * 9];
  float mx = v9[8];  // sorted ascending
  float sum = 0.f, mxe = 0.f;
  for (int i = 0; i < 9; ++i) {
    float e = expf(v9[i] - mx);
    sum += e;
    if (e > mxe) mxe = e;
  }
  out[b] = (1.f - mxe / sum) * bestv;
}

// ---------------- launch ----------------
extern "C" void kernel_launch(void* const* d_in, const int* in_sizes, int n_in,
                              void* d_out, int out_size, void* d_ws, size_t ws_size,
                              hipStream_t stream) {
  const float* x = (const float*)d_in[0];
  const float* mem = (const float*)d_in[1];
  float* out = (float*)d_out;
  char* ws = (char*)d_ws;

  // ws layout (needs ~87.7 MB)
  unsigned short* xbf = (unsigned short*)(ws);                 // 19,267,584 B
  unsigned short* mbf = (unsigned short*)(ws + 19267584);      // 61,734,912 B
  float* x2      = (float*)(ws + 81002496);                    // 25,088 B
  float* m2      = (float*)(ws + 81027584);                    // 80,384 B
  float* partial = (float*)(ws + 81107968);                    // 3,938,816 B
  float* closest = (float*)(ws + 85046784);                    // 25,088 B
  int*   cand    = (int*)  (ws + 85071872);                    // 128 B
  float* dist    = (float*)(ws + 85072000);                    // 2,560,000 B
  float* top9    = (float*)(ws + 87632000);                    // 1,152 B

  convert_rows<<<NPAD_, 256, 0, stream>>>(mem, mbf, m2, N_);
  convert_rows<<<M_, 256, 0, stream>>>(x, xbf, x2, M_);
  gemm_min_kernel<<<NT_ * MT_, 256, 0, stream>>>(xbf, mbf, m2, partial);
  reduce_min_kernel<<<(M_ + 255) / 256, 256, 0, stream>>>(partial, x2, closest);
  topcand_kernel<<<B_, 256, 0, stream>>>(closest, cand);
  cand_dist_kernel<<<dim3((N_ + 63) / 64), 256, 0, stream>>>(x, mem, x2, m2, cand, dist);
  top9_kernel<<<B_ * NC_, 256, 0, stream>>>(dist, top9);
  score_kernel<<<1, 64, 0, stream>>>(top9, cand, out);
}

// Round 4
// 690.787 us; speedup vs baseline: 1.1965x; 1.1666x over previous
//
#include <hip/hip_runtime.h>
#include <math.h>

// Problem constants (reference: B,P,D,N,K = 8,784,1536,20000,9)
#define B_    8
#define P_    784
#define M_    6272      // B*P
#define D_    1536
#define N_    20000
#define NC_   4         // candidate patches per image

// 256x256 8-phase GEMM geometry
#define MPAD  6400      // 25*256
#define NPAD2 20224     // 79*256
#define MT2   25
#define NT2   79
#define KT2   24        // 1536/64 K-tiles

using bf16x8 = __attribute__((ext_vector_type(8))) __bf16;
using f32x4v = __attribute__((ext_vector_type(4))) float;

#define GLD_LDS16(src, dst)                                            \
  __builtin_amdgcn_global_load_lds(                                    \
      (__attribute__((address_space(1))) const void*)(src),            \
      (__attribute__((address_space(3))) void*)(dst), 16, 0, 0)

__device__ __forceinline__ unsigned short f2bf(float f) {
  union { float f; unsigned u; } v; v.f = f;
  unsigned r = v.u + 0x7fffu + ((v.u >> 16) & 1u);
  return (unsigned short)(r >> 16);
}

// ---------------- K0/K1: fp32 -> bf16 rows + row sum-of-squares (vectorized) ----------------
__global__ void convert_rows(const float* __restrict__ src,
                             unsigned short* __restrict__ dst,
                             float* __restrict__ sq, int realrows) {
  const int row = blockIdx.x;
  const int t = threadIdx.x;
  if (row >= realrows) {
    ushort4* w4 = (ushort4*)(dst + (size_t)row * D_);
    for (int i = t; i < D_ / 4; i += 256) w4[i] = ushort4{0, 0, 0, 0};
    if (t == 0) sq[row] = 1e30f;
    return;
  }
  const float4* r4 = (const float4*)(src + (size_t)row * D_);
  ushort4* w4 = (ushort4*)(dst + (size_t)row * D_);
  float s = 0.f;
  for (int i = t; i < D_ / 4; i += 256) {
    float4 v = r4[i];
    s += v.x * v.x + v.y * v.y + v.z * v.z + v.w * v.w;
    w4[i] = ushort4{f2bf(v.x), f2bf(v.y), f2bf(v.z), f2bf(v.w)};
  }
#pragma unroll
  for (int m = 32; m >= 1; m >>= 1) s += __shfl_xor(s, m);
  __shared__ float ws4[4];
  if ((t & 63) == 0) ws4[t >> 6] = s;
  __syncthreads();
  if (t == 0) sq[row] = ws4[0] + ws4[1] + ws4[2] + ws4[3];
}

// ---------------- K2: 256x256 8-phase bf16 MFMA GEMM with fused row-min epilogue ----------------
// LDS: A/B double-buffered [matrix][buf] 32KB each = 128KB, XOR-swizzled (T2),
// counted vmcnt (T4), per-phase interleave (T3), setprio around MFMA (T5).
// Swizzle: LDS byte-in-row ^= ((row&7)<<4); writer uses inverse-swizzled global source.
__global__ __launch_bounds__(512, 2) void gemm_min8(
    const unsigned short* __restrict__ xbf, const unsigned short* __restrict__ mbf,
    const float* __restrict__ m2, float* __restrict__ partial) {
  __shared__ __attribute__((aligned(16))) char ldsFlat[131072];
  __shared__ float ldsMin[4][256];

  // --- block swizzle: bijective XCD chunking + 5-mTile supertiles ---
  const int NWG = MT2 * NT2;              // 1975
  const int bid = blockIdx.x;
  const int q = NWG >> 3, r = NWG & 7;    // 246, 7
  const int xcd = bid & 7, loc = bid >> 3;
  const int wg = (xcd < r ? xcd * (q + 1) : r * (q + 1) + (xcd - r) * q) + loc;
  const int s = wg / (5 * NT2);
  const int r2 = wg - s * (5 * NT2);
  const int mT = s * 5 + (r2 % 5);
  const int nT = r2 / 5;

  const int tid = threadIdx.x;
  const int lane = tid & 63, wid = tid >> 6;
  const int wm = wid >> 2, wn = wid & 3;      // 2 x 4 wave grid
  const int g = lane >> 4, r16 = lane & 15;
  const int mBase = mT * 256, nBase = nT * 256;

  // staging addresses (per-thread): row-in-tile for stages, inverse-swizzled col
  const int stRow = wid * 8 + (lane >> 3);
  const int stA = mBase + stRow;
  const int stB = nBase + stRow;
  const int cswz8 = ((lane & 7) ^ ((lane >> 3) & 7)) * 8;  // element offset

  // reader offsets (bytes): row*128 + swizzled col
  const int cs0 = (g * 16) ^ ((r16 & 7) << 4);
  const int rdA = wm * 16384 + r16 * 128;          // + mf*2048 (+ buf*32768)
  const int rdB = wn * 8192 + r16 * 128;           // + nf*2048 (+ 65536 + buf*32768)

#define STAGE(matsel, srcp, rowb, bufb, h, ktv) do {                       \
    char* dst_ = ldsFlat + (matsel) * 65536 + (bufb) * 32768 +             \
                 (h) * 16384 + wid * 1024;                                 \
    const unsigned short* s_ =                                             \
        (srcp) + (size_t)((rowb) + (h) * 128) * 1536 + (ktv) * 64 + cswz8; \
    GLD_LDS16(s_, dst_);                                                   \
    GLD_LDS16(s_ + 64 * 1536, dst_ + 8192);                                \
  } while (0)

  f32x4v acc[8][4];
#pragma unroll
  for (int i = 0; i < 8; ++i)
#pragma unroll
    for (int j = 0; j < 4; ++j) acc[i][j] = f32x4v{0.f, 0.f, 0.f, 0.f};

  // ---- prologue: B(0) halves, A(0) halves, B(1) halves; wait first 8 of 12 ----
  STAGE(1, mbf, stB, 0, 0, 0);
  STAGE(1, mbf, stB, 0, 1, 0);
  STAGE(0, xbf, stA, 0, 0, 0);
  STAGE(0, xbf, stA, 0, 1, 0);
  STAGE(1, mbf, stB, 1, 0, 1);
  STAGE(1, mbf, stB, 1, 1, 1);
  asm volatile("s_waitcnt vmcnt(4)");
  __builtin_amdgcn_s_barrier();
  __builtin_amdgcn_sched_barrier(0);

#pragma unroll 1
  for (int kt = 0; kt < KT2; ++kt) {
    const int bufc = kt & 1;
    const char* Ab = ldsFlat + bufc * 32768;
    const char* Bb = ldsFlat + 65536 + bufc * 32768;
    const bool stgA = (kt + 1) < KT2;
    const bool stgB = (kt + 2) < KT2;
    bf16x8 b0[4], b1[4], av[4];

    // ---- phase 1: mf0-3 x ksub0 ; stage A0(kt+1) -> other buf ----
#pragma unroll
    for (int nf = 0; nf < 4; ++nf)
      b0[nf] = *(const bf16x8*)(Bb + rdB + nf * 2048 + cs0);
#pragma unroll
    for (int mf = 0; mf < 4; ++mf)
      av[mf] = *(const bf16x8*)(Ab + rdA + mf * 2048 + cs0);
    if (stgA) STAGE(0, xbf, stA, bufc ^ 1, 0, kt + 1);
    __builtin_amdgcn_s_barrier();
    asm volatile("s_waitcnt lgkmcnt(0)");
    __builtin_amdgcn_s_setprio(1);
#pragma unroll
    for (int mf = 0; mf < 4; ++mf)
#pragma unroll
      for (int nf = 0; nf < 4; ++nf)
        acc[mf][nf] = __builtin_amdgcn_mfma_f32_16x16x32_bf16(av[mf], b0[nf], acc[mf][nf], 0, 0, 0);
    __builtin_amdgcn_s_setprio(0);
    __builtin_amdgcn_s_barrier();

    // ---- phase 2: mf0-3 x ksub1 ; stage A1(kt+1) ----
#pragma unroll
    for (int nf = 0; nf < 4; ++nf)
      b1[nf] = *(const bf16x8*)(Bb + rdB + nf * 2048 + (cs0 ^ 64));
#pragma unroll
    for (int mf = 0; mf < 4; ++mf)
      av[mf] = *(const bf16x8*)(Ab + rdA + mf * 2048 + (cs0 ^ 64));
    if (stgA) STAGE(0, xbf, stA, bufc ^ 1, 1, kt + 1);
    __builtin_amdgcn_s_barrier();
    asm volatile("s_waitcnt lgkmcnt(0)");
    __builtin_amdgcn_s_setprio(1);
#pragma unroll
    for (int mf = 0; mf < 4; ++mf)
#pragma unroll
      for (int nf = 0; nf < 4; ++nf)
        acc[mf][nf] = __builtin_amdgcn_mfma_f32_16x16x32_bf16(av[mf], b1[nf], acc[mf][nf], 0, 0, 0);
    __builtin_amdgcn_s_setprio(0);
    __builtin_amdgcn_s_barrier();

    // ---- phase 3: mf4-7 x ksub0 ; stage B0(kt+2) -> same buf (B fully read) ----
#pragma unroll
    for (int mf = 0; mf < 4; ++mf)
      av[mf] = *(const bf16x8*)(Ab + rdA + (mf + 4) * 2048 + cs0);
    if (stgB) STAGE(1, mbf, stB, bufc, 0, kt + 2);
    __builtin_amdgcn_s_barrier();
    asm volatile("s_waitcnt lgkmcnt(0)");
    __builtin_amdgcn_s_setprio(1);
#pragma unroll
    for (int mf = 0; mf < 4; ++mf)
#pragma unroll
      for (int nf = 0; nf < 4; ++nf)
        acc[mf + 4][nf] = __builtin_amdgcn_mfma_f32_16x16x32_bf16(av[mf], b0[nf], acc[mf + 4][nf], 0, 0, 0);
    __builtin_amdgcn_s_setprio(0);
    __builtin_amdgcn_s_barrier();

    // ---- phase 4: mf4-7 x ksub1 ; stage B1(kt+2) ; counted vmcnt; boundary ----
#pragma unroll
    for (int mf = 0; mf < 4; ++mf)
      av[mf] = *(const bf16x8*)(Ab + rdA + (mf + 4) * 2048 + (cs0 ^ 64));
    if (stgB) STAGE(1, mbf, stB, bufc, 1, kt + 2);
    __builtin_amdgcn_s_barrier();
    asm volatile("s_waitcnt lgkmcnt(0)");
    __builtin_amdgcn_s_setprio(1);
#pragma unroll
    for (int mf = 0; mf < 4; ++mf)
#pragma unroll
      for (int nf = 0; nf < 4; ++nf)
        acc[mf + 4][nf] = __builtin_amdgcn_mfma_f32_16x16x32_bf16(av[mf], b1[nf], acc[mf + 4][nf], 0, 0, 0);
    __builtin_amdgcn_s_setprio(0);
    if (kt >= 22) {  // tail: stages were skipped, counts shift -> full drain
      asm volatile("s_waitcnt vmcnt(0)");
    } else {         // steady: allow B(kt+2)'s 4 loads outstanding
      asm volatile("s_waitcnt vmcnt(4)");
    }
    __builtin_amdgcn_s_barrier();
    __builtin_amdgcn_sched_barrier(0);
  }
#undef STAGE

  // ---- epilogue: per-row min over this tile's 256 cols ----
  // C/D layout: col = nBase + wn*64 + nf*16 + (lane&15), row = wm*128 + mf*16 + (lane>>4)*4 + i
  float m2v[4];
#pragma unroll
  for (int nf = 0; nf < 4; ++nf) m2v[nf] = m2[nBase + wn * 64 + nf * 16 + r16];
#pragma unroll
  for (int mf = 0; mf < 8; ++mf) {
    float mn[4];
#pragma unroll
    for (int i = 0; i < 4; ++i) {
      float v = m2v[0] - 2.f * acc[mf][0][i];
      v = fminf(v, m2v[1] - 2.f * acc[mf][1][i]);
      v = fminf(v, m2v[2] - 2.f * acc[mf][2][i]);
      v = fminf(v, m2v[3] - 2.f * acc[mf][3][i]);
      mn[i] = v;
    }
#pragma unroll
    for (int msk = 1; msk < 16; msk <<= 1)
#pragma unroll
      for (int i = 0; i < 4; ++i) mn[i] = fminf(mn[i], __shfl_xor(mn[i], msk));
    if (r16 == 0)
#pragma unroll
      for (int i = 0; i < 4; ++i)
        ldsMin[wn][wm * 128 + mf * 16 + g * 4 + i] = mn[i];
  }
  __syncthreads();
  if (tid < 256) {
    float v = fminf(fminf(ldsMin[0][tid], ldsMin[1][tid]),
                    fminf(ldsMin[2][tid], ldsMin[3][tid]));
    partial[(size_t)nT * MPAD + mBase + tid] = v;
  }
}

// ---------------- K3: per image, closest = x2 + min over tiles; wave-parallel top-4 ----------------
__global__ void patch_reduce_kernel(const float* __restrict__ partial,
                                    const float* __restrict__ x2,
                                    int* __restrict__ cand) {
  const int b = blockIdx.x;
  const int t = threadIdx.x;
  __shared__ float cls[P_];
  for (int p = t; p < P_; p += 256) {
    const int row = b * P_ + p;
    float v = 3e38f;
    for (int nt = 0; nt < NT2; ++nt) v = fminf(v, partial[(size_t)nt * MPAD + row]);
    cls[p] = x2[row] + v;
  }
  __syncthreads();
  __shared__ float wv[4];
  __shared__ int wi_[4];
  __shared__ int picked[NC_];
  for (int r = 0; r < NC_; ++r) {
    float mv = -3e38f; int mi = 1 << 30;
    for (int p = t; p < P_; p += 256) {
      bool skip = false;
      for (int c = 0; c < r; ++c) skip |= (picked[c] == p);
      float v = cls[p];
      if (!skip && (v > mv || (v == mv && p < mi))) { mv = v; mi = p; }
    }
#pragma unroll
    for (int m = 32; m >= 1; m >>= 1) {
      float ov = __shfl_xor(mv, m); int oi = __shfl_xor(mi, m);
      if (ov > mv || (ov == mv && oi < mi)) { mv = ov; mi = oi; }
    }
    if ((t & 63) == 0) { wv[t >> 6] = mv; wi_[t >> 6] = mi; }
    __syncthreads();
    if (t == 0) {
      float bv = wv[0]; int bi = wi_[0];
      for (int w = 1; w < 4; ++w)
        if (wv[w] > bv || (wv[w] == bv && wi_[w] < bi)) { bv = wv[w]; bi = wi_[w]; }
      picked[r] = bi;
      cand[b * NC_ + r] = bi;
    }
    __syncthreads();
  }
}

// ---------------- K4: exact fp32 distances — ONE pass over the memory bank ----------------
__global__ __launch_bounds__(256) void cand_dist_kernel(
    const float* __restrict__ x, const float* __restrict__ mem,
    const float* __restrict__ x2, const float* __restrict__ m2,
    const int* __restrict__ cand, float* __restrict__ dist) {
  const int wid = threadIdx.x >> 6, lane = threadIdx.x & 63;
  const int row0 = blockIdx.x * 64 + wid * 16;
  for (int rr = 0; rr < 16; rr += 4) {
    const int rbase = row0 + rr;
    if (rbase >= N_) return;
    float4 m4[4][6];
    float m2r[4];
#pragma unroll
    for (int k = 0; k < 4; ++k) {
      const float4* mrow = (const float4*)(mem + (size_t)(rbase + k) * D_);
#pragma unroll
      for (int j = 0; j < 6; ++j) m4[k][j] = mrow[j * 64 + lane];
      m2r[k] = m2[rbase + k];
    }
    for (int bc = 0; bc < B_ * NC_; ++bc) {
      const int b = bc >> 2;
      const int p = cand[bc];
      const float4* xp = (const float4*)(x + ((size_t)b * P_ + p) * D_);
      float s0 = 0.f, s1 = 0.f, s2 = 0.f, s3 = 0.f;
#pragma unroll
      for (int j = 0; j < 6; ++j) {
        float4 a = xp[j * 64 + lane];
        s0 += a.x * m4[0][j].x + a.y * m4[0][j].y + a.z * m4[0][j].z + a.w * m4[0][j].w;
        s1 += a.x * m4[1][j].x + a.y * m4[1][j].y + a.z * m4[1][j].z + a.w * m4[1][j].w;
        s2 += a.x * m4[2][j].x + a.y * m4[2][j].y + a.z * m4[2][j].z + a.w * m4[2][j].w;
        s3 += a.x * m4[3][j].x + a.y * m4[3][j].y + a.z * m4[3][j].z + a.w * m4[3][j].w;
      }
#pragma unroll
      for (int msk = 32; msk >= 1; msk >>= 1) {
        s0 += __shfl_xor(s0, msk); s1 += __shfl_xor(s1, msk);
        s2 += __shfl_xor(s2, msk); s3 += __shfl_xor(s3, msk);
      }
      if (lane == 0) {
        const float xx = x2[b * P_ + p];
        dist[(size_t)bc * N_ + rbase + 0] = xx + m2r[0] - 2.f * s0;
        dist[(size_t)bc * N_ + rbase + 1] = xx + m2r[1] - 2.f * s1;
        dist[(size_t)bc * N_ + rbase + 2] = xx + m2r[2] - 2.f * s2;
        dist[(size_t)bc * N_ + rbase + 3] = xx + m2r[3] - 2.f * s3;
      }
    }
  }
}

// ---------------- K5: exact top-9 (ascending) per candidate ----------------
__device__ __forceinline__ void ins9(float* t, float v) {
  if (v < t[8]) {
    int p = 8;
    while (p > 0 && t[p - 1] > v) { t[p] = t[p - 1]; --p; }
    t[p] = v;
  }
}
__global__ void top9_kernel(const float* __restrict__ dist, float* __restrict__ top9) {
  const int bc = blockIdx.x;  // 0..31
  const float* d = dist + (size_t)bc * N_;
  float t[9];
#pragma unroll
  for (int i = 0; i < 9; ++i) t[i] = 3e38f;
  for (int n = threadIdx.x; n < N_; n += 256) ins9(t, d[n]);
  __shared__ float l9[256 * 9];
  __shared__ float l9b[32 * 9];
  for (int i = 0; i < 9; ++i) l9[threadIdx.x * 9 + i] = t[i];
  __syncthreads();
  if (threadIdx.x < 32) {
    float u[9];
#pragma unroll
    for (int i = 0; i < 9; ++i) u[i] = 3e38f;
    for (int s = 0; s < 8; ++s)
      for (int i = 0; i < 9; ++i) ins9(u, l9[(threadIdx.x * 8 + s) * 9 + i]);
    for (int i = 0; i < 9; ++i) l9b[threadIdx.x * 9 + i] = u[i];
  }
  __syncthreads();
  if (threadIdx.x == 0) {
    float u[9];
#pragma unroll
    for (int i = 0; i < 9; ++i) u[i] = 3e38f;
    for (int s = 0; s < 32; ++s)
      for (int i = 0; i < 9; ++i) ins9(u, l9b[s * 9 + i]);
    for (int i = 0; i < 9; ++i) top9[bc * 9 + i] = u[i];
  }
}

// ---------------- K6: pick exact argmax candidate, compute score ----------------
__global__ void score_kernel(const float* __restrict__ top9, const int* __restrict__ cand,
                             float* __restrict__ out) {
  const int b = threadIdx.x;
  if (b >= B_) return;
  float bestv = -3e38f; int bestc = 0, bestp = 1 << 30;
  for (int c = 0; c < NC_; ++c) {
    float v = top9[(b * NC_ + c) * 9 + 0];
    int p = cand[b * NC_ + c];
    if (v > bestv || (v == bestv && p < bestp)) { bestv = v; bestc = c; bestp = p; }
  }
  const float* v9 = &top9[(b * NC_ + bestc) * 9];
  float mx = v9[8];  // sorted ascending
  float sum = 0.f, mxe = 0.f;
  for (int i = 0; i < 9; ++i) {
    float e = expf(v9[i] - mx);
    sum += e;
    if (e > mxe) mxe = e;
  }
  out[b] = (1.f - mxe / sum) * bestv;
}

// ---------------- launch ----------------
extern "C" void kernel_launch(void* const* d_in, const int* in_sizes, int n_in,
                              void* d_out, int out_size, void* d_ws, size_t ws_size,
                              hipStream_t stream) {
  const float* x = (const float*)d_in[0];
  const float* mem = (const float*)d_in[1];
  float* out = (float*)d_out;
  char* ws = (char*)d_ws;

  // ws layout (~86.5 MB)
  unsigned short* xbf = (unsigned short*)(ws);                  // 19,660,800
  unsigned short* mbf = (unsigned short*)(ws + 19660800);       // 62,128,128
  float* x2      = (float*)(ws + 81788928);                     // 25,600
  float* m2      = (float*)(ws + 81814528);                     // 80,896
  float* partial = (float*)(ws + 81895424);                     // 2,022,400
  int*   cand    = (int*)  (ws + 83917824);                     // 128
  float* dist    = (float*)(ws + 83917952);                     // 2,560,000
  float* top9    = (float*)(ws + 86477952);                     // 1,152

  convert_rows<<<NPAD2, 256, 0, stream>>>(mem, mbf, m2, N_);
  convert_rows<<<MPAD, 256, 0, stream>>>(x, xbf, x2, M_);
  gemm_min8<<<MT2 * NT2, 512, 0, stream>>>(xbf, mbf, m2, partial);
  patch_reduce_kernel<<<B_, 256, 0, stream>>>(partial, x2, cand);
  cand_dist_kernel<<<(N_ + 63) / 64, 256, 0, stream>>>(x, mem, x2, m2, cand, dist);
  top9_kernel<<<B_ * NC_, 256, 0, stream>>>(dist, top9);
  score_kernel<<<1, 64, 0, stream>>>(top9, cand, out);
}

// Round 5
// 585.705 us; speedup vs baseline: 1.4112x; 1.1794x over previous
//
#include <hip/hip_runtime.h>
#include <math.h>

// Problem constants (reference: B,P,D,N,K = 8,784,1536,20000,9)
#define B_    8
#define P_    784
#define M_    6272      // B*P
#define D_    1536
#define N_    20000
#define NC_   4         // candidate patches per image

// 256x256 8-phase GEMM geometry
#define MPAD  6400      // 25*256
#define NPAD2 20224     // 79*256
#define MT2   25
#define NT2   79
#define KT2   24        // 1536/64 K-tiles

#define NBLK  313       // cand-dist blocks of 64 rows (313*64 = 20032)

using bf16x8 = __attribute__((ext_vector_type(8))) __bf16;
using f32x4v = __attribute__((ext_vector_type(4))) float;

#define GLD_LDS16(src, dst)                                            \
  __builtin_amdgcn_global_load_lds(                                    \
      (__attribute__((address_space(1))) const void*)(src),            \
      (__attribute__((address_space(3))) void*)(dst), 16, 0, 0)

__device__ __forceinline__ unsigned short f2bf(float f) {
  union { float f; unsigned u; } v; v.f = f;
  unsigned r = v.u + 0x7fffu + ((v.u >> 16) & 1u);
  return (unsigned short)(r >> 16);
}

// order-preserving float<->uint for atomicMin (all finite values)
__device__ __forceinline__ unsigned fenc(float f) {
  unsigned u = __float_as_uint(f);
  return (u >> 31) ? ~u : (u | 0x80000000u);
}
__device__ __forceinline__ float fdec(unsigned k) {
  return (k >> 31) ? __uint_as_float(k & 0x7FFFFFFFu) : __uint_as_float(~k);
}

// ---------------- K1: fused fp32 -> bf16 + row sum-of-squares for BOTH matrices ----------------
__device__ __forceinline__ void convert_one(const float* __restrict__ src,
                                            unsigned short* __restrict__ dst,
                                            float* __restrict__ sq,
                                            int row, int realrows) {
  const int t = threadIdx.x;
  if (row >= realrows) {
    ushort4* w4 = (ushort4*)(dst + (size_t)row * D_);
    for (int i = t; i < D_ / 4; i += 256) w4[i] = ushort4{0, 0, 0, 0};
    if (t == 0) sq[row] = 1e30f;
    return;
  }
  const float4* r4 = (const float4*)(src + (size_t)row * D_);
  ushort4* w4 = (ushort4*)(dst + (size_t)row * D_);
  float s = 0.f;
  for (int i = t; i < D_ / 4; i += 256) {
    float4 v = r4[i];
    s += v.x * v.x + v.y * v.y + v.z * v.z + v.w * v.w;
    w4[i] = ushort4{f2bf(v.x), f2bf(v.y), f2bf(v.z), f2bf(v.w)};
  }
#pragma unroll
  for (int m = 32; m >= 1; m >>= 1) s += __shfl_xor(s, m);
  __shared__ float ws4[4];
  if ((t & 63) == 0) ws4[t >> 6] = s;
  __syncthreads();
  if (t == 0) sq[row] = ws4[0] + ws4[1] + ws4[2] + ws4[3];
}

__global__ void convert_all(const float* __restrict__ x, const float* __restrict__ mem,
                            unsigned short* __restrict__ xbf, unsigned short* __restrict__ mbf,
                            float* __restrict__ x2, float* __restrict__ m2) {
  const int blk = blockIdx.x;
  if (blk < NPAD2) convert_one(mem, mbf, m2, blk, N_);
  else convert_one(x, xbf, x2, blk - NPAD2, M_);
}

// ---------------- K2: 256x256 8-phase bf16 MFMA GEMM, epilogue -> atomicMin ----------------
// LDS: A/B double-buffered 128KB, XOR-swizzled (T2), counted vmcnt (T4),
// per-phase interleave (T3), setprio (T5). Swizzle byte^=((row&7)<<4),
// writer uses inverse-swizzled global source (both-sides rule #21).
__global__ __launch_bounds__(512, 2) void gemm_min8(
    const unsigned short* __restrict__ xbf, const unsigned short* __restrict__ mbf,
    const float* __restrict__ m2, unsigned* __restrict__ closest_enc) {
  __shared__ __attribute__((aligned(16))) char ldsFlat[131072];
  __shared__ float ldsMin[4][256];

  // --- block swizzle: bijective XCD chunking + 5-mTile supertiles ---
  const int NWG = MT2 * NT2;              // 1975
  const int bid = blockIdx.x;
  const int q = NWG >> 3, r = NWG & 7;    // 246, 7
  const int xcd = bid & 7, loc = bid >> 3;
  const int wg = (xcd < r ? xcd * (q + 1) : r * (q + 1) + (xcd - r) * q) + loc;
  const int s = wg / (5 * NT2);
  const int r2 = wg - s * (5 * NT2);
  const int mT = s * 5 + (r2 % 5);
  const int nT = r2 / 5;

  const int tid = threadIdx.x;
  const int lane = tid & 63, wid = tid >> 6;
  const int wm = wid >> 2, wn = wid & 3;      // 2 x 4 wave grid
  const int g = lane >> 4, r16 = lane & 15;
  const int mBase = mT * 256, nBase = nT * 256;

  const int stRow = wid * 8 + (lane >> 3);
  const int stA = mBase + stRow;
  const int stB = nBase + stRow;
  const int cswz8 = ((lane & 7) ^ ((lane >> 3) & 7)) * 8;  // inverse-swizzled col (elements)

  const int cs0 = (g * 16) ^ ((r16 & 7) << 4);
  const int rdA = wm * 16384 + r16 * 128;          // + mf*2048 (+ buf*32768)
  const int rdB = wn * 8192 + r16 * 128;           // + nf*2048 (+ 65536 + buf*32768)

#define STAGE(matsel, srcp, rowb, bufb, h, ktv) do {                       \
    char* dst_ = ldsFlat + (matsel) * 65536 + (bufb) * 32768 +             \
                 (h) * 16384 + wid * 1024;                                 \
    const unsigned short* s_ =                                             \
        (srcp) + (size_t)((rowb) + (h) * 128) * 1536 + (ktv) * 64 + cswz8; \
    GLD_LDS16(s_, dst_);                                                   \
    GLD_LDS16(s_ + 64 * 1536, dst_ + 8192);                                \
  } while (0)

  f32x4v acc[8][4];
#pragma unroll
  for (int i = 0; i < 8; ++i)
#pragma unroll
    for (int j = 0; j < 4; ++j) acc[i][j] = f32x4v{0.f, 0.f, 0.f, 0.f};

  // ---- prologue: B(0), A(0), B(1); wait first 8 of 12 loads ----
  STAGE(1, mbf, stB, 0, 0, 0);
  STAGE(1, mbf, stB, 0, 1, 0);
  STAGE(0, xbf, stA, 0, 0, 0);
  STAGE(0, xbf, stA, 0, 1, 0);
  STAGE(1, mbf, stB, 1, 0, 1);
  STAGE(1, mbf, stB, 1, 1, 1);
  asm volatile("s_waitcnt vmcnt(4)");
  __builtin_amdgcn_s_barrier();
  __builtin_amdgcn_sched_barrier(0);

#pragma unroll 1
  for (int kt = 0; kt < KT2; ++kt) {
    const int bufc = kt & 1;
    const char* Ab = ldsFlat + bufc * 32768;
    const char* Bb = ldsFlat + 65536 + bufc * 32768;
    const bool stgA = (kt + 1) < KT2;
    const bool stgB = (kt + 2) < KT2;
    bf16x8 b0[4], b1[4], av[4];

    // ---- phase 1: mf0-3 x ksub0 ; stage A0(kt+1) -> other buf ----
#pragma unroll
    for (int nf = 0; nf < 4; ++nf)
      b0[nf] = *(const bf16x8*)(Bb + rdB + nf * 2048 + cs0);
#pragma unroll
    for (int mf = 0; mf < 4; ++mf)
      av[mf] = *(const bf16x8*)(Ab + rdA + mf * 2048 + cs0);
    if (stgA) STAGE(0, xbf, stA, bufc ^ 1, 0, kt + 1);
    __builtin_amdgcn_s_barrier();
    asm volatile("s_waitcnt lgkmcnt(0)");
    __builtin_amdgcn_s_setprio(1);
#pragma unroll
    for (int mf = 0; mf < 4; ++mf)
#pragma unroll
      for (int nf = 0; nf < 4; ++nf)
        acc[mf][nf] = __builtin_amdgcn_mfma_f32_16x16x32_bf16(av[mf], b0[nf], acc[mf][nf], 0, 0, 0);
    __builtin_amdgcn_s_setprio(0);
    __builtin_amdgcn_s_barrier();

    // ---- phase 2: mf0-3 x ksub1 ; stage A1(kt+1) ----
#pragma unroll
    for (int nf = 0; nf < 4; ++nf)
      b1[nf] = *(const bf16x8*)(Bb + rdB + nf * 2048 + (cs0 ^ 64));
#pragma unroll
    for (int mf = 0; mf < 4; ++mf)
      av[mf] = *(const bf16x8*)(Ab + rdA + mf * 2048 + (cs0 ^ 64));
    if (stgA) STAGE(0, xbf, stA, bufc ^ 1, 1, kt + 1);
    __builtin_amdgcn_s_barrier();
    asm volatile("s_waitcnt lgkmcnt(0)");
    __builtin_amdgcn_s_setprio(1);
#pragma unroll
    for (int mf = 0; mf < 4; ++mf)
#pragma unroll
      for (int nf = 0; nf < 4; ++nf)
        acc[mf][nf] = __builtin_amdgcn_mfma_f32_16x16x32_bf16(av[mf], b1[nf], acc[mf][nf], 0, 0, 0);
    __builtin_amdgcn_s_setprio(0);
    __builtin_amdgcn_s_barrier();

    // ---- phase 3: mf4-7 x ksub0 ; stage B0(kt+2) -> same buf (B fully read) ----
#pragma unroll
    for (int mf = 0; mf < 4; ++mf)
      av[mf] = *(const bf16x8*)(Ab + rdA + (mf + 4) * 2048 + cs0);
    if (stgB) STAGE(1, mbf, stB, bufc, 0, kt + 2);
    __builtin_amdgcn_s_barrier();
    asm volatile("s_waitcnt lgkmcnt(0)");
    __builtin_amdgcn_s_setprio(1);
#pragma unroll
    for (int mf = 0; mf < 4; ++mf)
#pragma unroll
      for (int nf = 0; nf < 4; ++nf)
        acc[mf + 4][nf] = __builtin_amdgcn_mfma_f32_16x16x32_bf16(av[mf], b0[nf], acc[mf + 4][nf], 0, 0, 0);
    __builtin_amdgcn_s_setprio(0);
    __builtin_amdgcn_s_barrier();

    // ---- phase 4: mf4-7 x ksub1 ; stage B1(kt+2) ; counted vmcnt; boundary ----
#pragma unroll
    for (int mf = 0; mf < 4; ++mf)
      av[mf] = *(const bf16x8*)(Ab + rdA + (mf + 4) * 2048 + (cs0 ^ 64));
    if (stgB) STAGE(1, mbf, stB, bufc, 1, kt + 2);
    __builtin_amdgcn_s_barrier();
    asm volatile("s_waitcnt lgkmcnt(0)");
    __builtin_amdgcn_s_setprio(1);
#pragma unroll
    for (int mf = 0; mf < 4; ++mf)
#pragma unroll
      for (int nf = 0; nf < 4; ++nf)
        acc[mf + 4][nf] = __builtin_amdgcn_mfma_f32_16x16x32_bf16(av[mf], b1[nf], acc[mf + 4][nf], 0, 0, 0);
    __builtin_amdgcn_s_setprio(0);
    if (kt >= 22) {  // tail: stages skipped, counts shift -> full drain
      asm volatile("s_waitcnt vmcnt(0)");
    } else {         // steady: allow B(kt+2)'s 4 loads outstanding
      asm volatile("s_waitcnt vmcnt(4)");
    }
    __builtin_amdgcn_s_barrier();
    __builtin_amdgcn_sched_barrier(0);
  }
#undef STAGE

  // ---- epilogue: per-row min over this tile's 256 cols -> global atomicMin ----
  float m2v[4];
#pragma unroll
  for (int nf = 0; nf < 4; ++nf) m2v[nf] = m2[nBase + wn * 64 + nf * 16 + r16];
#pragma unroll
  for (int mf = 0; mf < 8; ++mf) {
    float mn[4];
#pragma unroll
    for (int i = 0; i < 4; ++i) {
      float v = m2v[0] - 2.f * acc[mf][0][i];
      v = fminf(v, m2v[1] - 2.f * acc[mf][1][i]);
      v = fminf(v, m2v[2] - 2.f * acc[mf][2][i]);
      v = fminf(v, m2v[3] - 2.f * acc[mf][3][i]);
      mn[i] = v;
    }
#pragma unroll
    for (int msk = 1; msk < 16; msk <<= 1)
#pragma unroll
      for (int i = 0; i < 4; ++i) mn[i] = fminf(mn[i], __shfl_xor(mn[i], msk));
    if (r16 == 0)
#pragma unroll
      for (int i = 0; i < 4; ++i)
        ldsMin[wn][wm * 128 + mf * 16 + g * 4 + i] = mn[i];
  }
  __syncthreads();
  if (tid < 256) {
    float v = fminf(fminf(ldsMin[0][tid], ldsMin[1][tid]),
                    fminf(ldsMin[2][tid], ldsMin[3][tid]));
    atomicMin(&closest_enc[mBase + tid], fenc(v));
  }
}

// ---------------- K3: per image, closest = x2 + decoded min; wave-parallel top-4 ----------------
__global__ void topcand_kernel(const unsigned* __restrict__ closest_enc,
                               const float* __restrict__ x2,
                               int* __restrict__ cand) {
  const int b = blockIdx.x;
  const int t = threadIdx.x;
  __shared__ float cls[P_];
  for (int p = t; p < P_; p += 256) {
    const int row = b * P_ + p;
    cls[p] = x2[row] + fdec(closest_enc[row]);
  }
  __syncthreads();
  __shared__ float wv[4];
  __shared__ int wi_[4];
  __shared__ int picked[NC_];
  for (int r = 0; r < NC_; ++r) {
    float mv = -3e38f; int mi = 1 << 30;
    for (int p = t; p < P_; p += 256) {
      bool skip = false;
      for (int c = 0; c < r; ++c) skip |= (picked[c] == p);
      float v = cls[p];
      if (!skip && (v > mv || (v == mv && p < mi))) { mv = v; mi = p; }
    }
#pragma unroll
    for (int m = 32; m >= 1; m >>= 1) {
      float ov = __shfl_xor(mv, m); int oi = __shfl_xor(mi, m);
      if (ov > mv || (ov == mv && oi < mi)) { mv = ov; mi = oi; }
    }
    if ((t & 63) == 0) { wv[t >> 6] = mv; wi_[t >> 6] = mi; }
    __syncthreads();
    if (t == 0) {
      float bv = wv[0]; int bi = wi_[0];
      for (int w = 1; w < 4; ++w)
        if (wv[w] > bv || (wv[w] == bv && wi_[w] < bi)) { bv = wv[w]; bi = wi_[w]; }
      picked[r] = bi;
      cand[b * NC_ + r] = bi;
    }
    __syncthreads();
  }
}

__device__ __forceinline__ void ins9(float* t, float v) {
  if (v < t[8]) {
    int p = 8;
    while (p > 0 && t[p - 1] > v) { t[p] = t[p - 1]; --p; }
    t[p] = v;
  }
}

// ---------------- K4: exact fp32 distances, ONE pass over memory + per-block top-9 ----------------
// Block: 64 rows (4 waves x 16). Distances -> LDS[32 cand][64 rows]; then 8 lanes/wave
// each insertion-scan one candidate's 64 values -> ctop[bc][blk][9].
__global__ __launch_bounds__(256) void cand_dist9(
    const float* __restrict__ x, const float* __restrict__ mem,
    const float* __restrict__ x2, const float* __restrict__ m2,
    const int* __restrict__ cand, float* __restrict__ ctop) {
  const int wid = threadIdx.x >> 6, lane = threadIdx.x & 63;
  const int blk = blockIdx.x;
  const int row0 = blk * 64 + wid * 16;
  __shared__ float ldsD[32][72];  // [cand][row-in-block], padded to 72 (bank spread)

  for (int rr = 0; rr < 16; rr += 4) {
    const int rbase = row0 + rr;
    if (rbase + 3 < N_) {
      float4 m4[4][6];
      float m2r[4];
#pragma unroll
      for (int k = 0; k < 4; ++k) {
        const float4* mrow = (const float4*)(mem + (size_t)(rbase + k) * D_);
#pragma unroll
        for (int j = 0; j < 6; ++j) m4[k][j] = mrow[j * 64 + lane];
        m2r[k] = m2[rbase + k];
      }
      for (int bc = 0; bc < B_ * NC_; ++bc) {
        const int b = bc >> 2;
        const int p = cand[bc];
        const float4* xp = (const float4*)(x + ((size_t)b * P_ + p) * D_);
        float s0 = 0.f, s1 = 0.f, s2 = 0.f, s3 = 0.f;
#pragma unroll
        for (int j = 0; j < 6; ++j) {
          float4 a = xp[j * 64 + lane];
          s0 += a.x * m4[0][j].x + a.y * m4[0][j].y + a.z * m4[0][j].z + a.w * m4[0][j].w;
          s1 += a.x * m4[1][j].x + a.y * m4[1][j].y + a.z * m4[1][j].z + a.w * m4[1][j].w;
          s2 += a.x * m4[2][j].x + a.y * m4[2][j].y + a.z * m4[2][j].z + a.w * m4[2][j].w;
          s3 += a.x * m4[3][j].x + a.y * m4[3][j].y + a.z * m4[3][j].z + a.w * m4[3][j].w;
        }
#pragma unroll
        for (int msk = 32; msk >= 1; msk >>= 1) {
          s0 += __shfl_xor(s0, msk); s1 += __shfl_xor(s1, msk);
          s2 += __shfl_xor(s2, msk); s3 += __shfl_xor(s3, msk);
        }
        if (lane == 0) {
          const float xx = x2[b * P_ + p];
          const int rloc = wid * 16 + rr;
          ldsD[bc][rloc + 0] = xx + m2r[0] - 2.f * s0;
          ldsD[bc][rloc + 1] = xx + m2r[1] - 2.f * s1;
          ldsD[bc][rloc + 2] = xx + m2r[2] - 2.f * s2;
          ldsD[bc][rloc + 3] = xx + m2r[3] - 2.f * s3;
        }
      }
    } else {
      if (lane < 32) {
        const int rloc = wid * 16 + rr;
#pragma unroll
        for (int k = 0; k < 4; ++k) ldsD[lane][rloc + k] = 3e38f;
      }
    }
  }
  __syncthreads();
  if (lane < 8) {
    const int bc = wid * 8 + lane;
    float t[9];
#pragma unroll
    for (int i = 0; i < 9; ++i) t[i] = 3e38f;
    for (int i = 0; i < 64; ++i) ins9(t, ldsD[bc][i]);
    float* o = ctop + ((size_t)bc * NBLK + blk) * 9;
#pragma unroll
    for (int i = 0; i < 9; ++i) o[i] = t[i];
  }
}

// ---------------- K5: merge per-block top-9 partials -> exact top-9 per candidate ----------------
__global__ void merge_top9(const float* __restrict__ ctop, float* __restrict__ top9) {
  const int bc = blockIdx.x;  // 0..31
  const float* d = ctop + (size_t)bc * (NBLK * 9);
  float t[9];
#pragma unroll
  for (int i = 0; i < 9; ++i) t[i] = 3e38f;
  for (int n = threadIdx.x; n < NBLK * 9; n += 256) ins9(t, d[n]);
  __shared__ float l9[256 * 9];
  __shared__ float l9b[32 * 9];
  for (int i = 0; i < 9; ++i) l9[threadIdx.x * 9 + i] = t[i];
  __syncthreads();
  if (threadIdx.x < 32) {
    float u[9];
#pragma unroll
    for (int i = 0; i < 9; ++i) u[i] = 3e38f;
    for (int s = 0; s < 8; ++s)
      for (int i = 0; i < 9; ++i) ins9(u, l9[(threadIdx.x * 8 + s) * 9 + i]);
    for (int i = 0; i < 9; ++i) l9b[threadIdx.x * 9 + i] = u[i];
  }
  __syncthreads();
  if (threadIdx.x == 0) {
    float u[9];
#pragma unroll
    for (int i = 0; i < 9; ++i) u[i] = 3e38f;
    for (int s = 0; s < 32; ++s)
      for (int i = 0; i < 9; ++i) ins9(u, l9b[s * 9 + i]);
    for (int i = 0; i < 9; ++i) top9[bc * 9 + i] = u[i];
  }
}

// ---------------- K6: pick exact argmax candidate, compute score ----------------
__global__ void score_kernel(const float* __restrict__ top9, const int* __restrict__ cand,
                             float* __restrict__ out) {
  const int b = threadIdx.x;
  if (b >= B_) return;
  float bestv = -3e38f; int bestc = 0, bestp = 1 << 30;
  for (int c = 0; c < NC_; ++c) {
    float v = top9[(b * NC_ + c) * 9 + 0];
    int p = cand[b * NC_ + c];
    if (v > bestv || (v == bestv && p < bestp)) { bestv = v; bestc = c; bestp = p; }
  }
  const float* v9 = &top9[(b * NC_ + bestc) * 9];
  float mx = v9[8];  // sorted ascending
  float sum = 0.f, mxe = 0.f;
  for (int i = 0; i < 9; ++i) {
    float e = expf(v9[i] - mx);
    sum += e;
    if (e > mxe) mxe = e;
  }
  out[b] = (1.f - mxe / sum) * bestv;
}

// ---------------- launch ----------------
extern "C" void kernel_launch(void* const* d_in, const int* in_sizes, int n_in,
                              void* d_out, int out_size, void* d_ws, size_t ws_size,
                              hipStream_t stream) {
  const float* x = (const float*)d_in[0];
  const float* mem = (const float*)d_in[1];
  float* out = (float*)d_out;
  char* ws = (char*)d_ws;

  // ws layout (~82.3 MB)
  unsigned short* xbf  = (unsigned short*)(ws);                 // 19,660,800
  unsigned short* mbf  = (unsigned short*)(ws + 19660800);      // 62,128,128
  float* x2            = (float*)(ws + 81788928);               // 25,600
  float* m2            = (float*)(ws + 81814528);               // 80,896
  unsigned* closest_enc= (unsigned*)(ws + 81895424);            // 25,600
  int*   cand          = (int*)  (ws + 81921024);               // 128
  float* ctop          = (float*)(ws + 81921152);               // 360,576
  float* top9          = (float*)(ws + 82281728);               // 1,152

  hipMemsetAsync(closest_enc, 0xFF, MPAD * 4, stream);
  convert_all<<<NPAD2 + MPAD, 256, 0, stream>>>(x, mem, xbf, mbf, x2, m2);
  gemm_min8<<<MT2 * NT2, 512, 0, stream>>>(xbf, mbf, m2, closest_enc);
  topcand_kernel<<<B_, 256, 0, stream>>>(closest_enc, x2, cand);
  cand_dist9<<<NBLK, 256, 0, stream>>>(x, mem, x2, m2, cand, ctop);
  merge_top9<<<B_ * NC_, 256, 0, stream>>>(ctop, top9);
  score_kernel<<<1, 64, 0, stream>>>(top9, cand, out);
}

// Round 6
// 551.472 us; speedup vs baseline: 1.4988x; 1.0621x over previous
//
#include <hip/hip_runtime.h>
#include <math.h>

// Problem constants (reference: B,P,D,N,K = 8,784,1536,20000,9)
#define B_    8
#define P_    784
#define M_    6272      // B*P
#define D_    1536
#define N_    20000
#define NC_   4         // candidate patches per image

// 256x256 GEMM geometry
#define MPAD  6400      // 25*256
#define NPAD2 20224     // 79*256
#define MT2   25
#define NT2   79
#define KT2   24        // 1536/64 K-tiles

#define NBLK  625       // cand-dist blocks of 32 rows (625*32 = 20000 exactly)

using bf16x8 = __attribute__((ext_vector_type(8))) __bf16;
using f32x4v = __attribute__((ext_vector_type(4))) float;

#define GLD_LDS16(src, dst)                                            \
  __builtin_amdgcn_global_load_lds(                                    \
      (__attribute__((address_space(1))) const void*)(src),            \
      (__attribute__((address_space(3))) void*)(dst), 16, 0, 0)

__device__ __forceinline__ unsigned short f2bf(float f) {
  union { float f; unsigned u; } v; v.f = f;
  unsigned r = v.u + 0x7fffu + ((v.u >> 16) & 1u);
  return (unsigned short)(r >> 16);
}

// order-preserving float<->uint for atomicMin (all finite values)
__device__ __forceinline__ unsigned fenc(float f) {
  unsigned u = __float_as_uint(f);
  return (u >> 31) ? ~u : (u | 0x80000000u);
}
__device__ __forceinline__ float fdec(unsigned k) {
  return (k >> 31) ? __uint_as_float(k & 0x7FFFFFFFu) : __uint_as_float(~k);
}

// ---------------- K1: fused fp32 -> bf16 + row sum-of-squares for BOTH matrices ----------------
__device__ __forceinline__ void convert_one(const float* __restrict__ src,
                                            unsigned short* __restrict__ dst,
                                            float* __restrict__ sq,
                                            int row, int realrows) {
  const int t = threadIdx.x;
  if (row >= realrows) {
    ushort4* w4 = (ushort4*)(dst + (size_t)row * D_);
    for (int i = t; i < D_ / 4; i += 256) w4[i] = ushort4{0, 0, 0, 0};
    if (t == 0) sq[row] = 1e30f;
    return;
  }
  const float4* r4 = (const float4*)(src + (size_t)row * D_);
  ushort4* w4 = (ushort4*)(dst + (size_t)row * D_);
  float s = 0.f;
  for (int i = t; i < D_ / 4; i += 256) {
    float4 v = r4[i];
    s += v.x * v.x + v.y * v.y + v.z * v.z + v.w * v.w;
    w4[i] = ushort4{f2bf(v.x), f2bf(v.y), f2bf(v.z), f2bf(v.w)};
  }
#pragma unroll
  for (int m = 32; m >= 1; m >>= 1) s += __shfl_xor(s, m);
  __shared__ float ws4[4];
  if ((t & 63) == 0) ws4[t >> 6] = s;
  __syncthreads();
  if (t == 0) sq[row] = ws4[0] + ws4[1] + ws4[2] + ws4[3];
}

__global__ void convert_all(const float* __restrict__ x, const float* __restrict__ mem,
                            unsigned short* __restrict__ xbf, unsigned short* __restrict__ mbf,
                            float* __restrict__ x2, float* __restrict__ m2) {
  const int blk = blockIdx.x;
  if (blk < NPAD2) convert_one(mem, mbf, m2, blk, N_);
  else convert_one(x, xbf, x2, blk - NPAD2, M_);
}

// ---------------- K2: 256x256 bf16 MFMA GEMM, 2 merged phases/K-tile, epilogue -> atomicMin ----
// B and A-ksub1 fragments register-double-buffered within the phase: 4 barriers/K-tile
// instead of 8, two lgkm drains instead of four, 32-MFMA clusters. T2 swizzle (0 conflicts),
// T4 counted vmcnt, T5 setprio retained. Swizzle byte^=((row&7)<<4), inverse-swizzled source.
__global__ __launch_bounds__(512, 2) void gemm_min8(
    const unsigned short* __restrict__ xbf, const unsigned short* __restrict__ mbf,
    const float* __restrict__ m2, unsigned* __restrict__ closest_enc) {
  __shared__ __attribute__((aligned(16))) char ldsFlat[131072];
  __shared__ float ldsMin[4][256];

  // --- block swizzle: bijective XCD chunking + 5-mTile supertiles ---
  const int NWG = MT2 * NT2;              // 1975
  const int bid = blockIdx.x;
  const int q = NWG >> 3, r = NWG & 7;    // 246, 7
  const int xcd = bid & 7, loc = bid >> 3;
  const int wg = (xcd < r ? xcd * (q + 1) : r * (q + 1) + (xcd - r) * q) + loc;
  const int s = wg / (5 * NT2);
  const int r2 = wg - s * (5 * NT2);
  const int mT = s * 5 + (r2 % 5);
  const int nT = r2 / 5;

  const int tid = threadIdx.x;
  const int lane = tid & 63, wid = tid >> 6;
  const int wm = wid >> 2, wn = wid & 3;      // 2 x 4 wave grid
  const int g = lane >> 4, r16 = lane & 15;
  const int mBase = mT * 256, nBase = nT * 256;

  const int stRow = wid * 8 + (lane >> 3);
  const int stA = mBase + stRow;
  const int stB = nBase + stRow;
  const int cswz8 = ((lane & 7) ^ ((lane >> 3) & 7)) * 8;  // inverse-swizzled col (elements)

  const int cs0 = (g * 16) ^ ((r16 & 7) << 4);
  const int rdA = wm * 16384 + r16 * 128;          // + mf*2048 (+ buf*32768)
  const int rdB = wn * 8192 + r16 * 128;           // + nf*2048 (+ 65536 + buf*32768)

#define STAGE(matsel, srcp, rowb, bufb, h, ktv) do {                       \
    char* dst_ = ldsFlat + (matsel) * 65536 + (bufb) * 32768 +             \
                 (h) * 16384 + wid * 1024;                                 \
    const unsigned short* s_ =                                             \
        (srcp) + (size_t)((rowb) + (h) * 128) * 1536 + (ktv) * 64 + cswz8; \
    GLD_LDS16(s_, dst_);                                                   \
    GLD_LDS16(s_ + 64 * 1536, dst_ + 8192);                                \
  } while (0)

  f32x4v acc[8][4];
#pragma unroll
  for (int i = 0; i < 8; ++i)
#pragma unroll
    for (int j = 0; j < 4; ++j) acc[i][j] = f32x4v{0.f, 0.f, 0.f, 0.f};

  // ---- prologue: B(0), A(0), B(1); wait first 8 of 12 loads ----
  STAGE(1, mbf, stB, 0, 0, 0);
  STAGE(1, mbf, stB, 0, 1, 0);
  STAGE(0, xbf, stA, 0, 0, 0);
  STAGE(0, xbf, stA, 0, 1, 0);
  STAGE(1, mbf, stB, 1, 0, 1);
  STAGE(1, mbf, stB, 1, 1, 1);
  asm volatile("s_waitcnt vmcnt(4)");
  __builtin_amdgcn_s_barrier();
  __builtin_amdgcn_sched_barrier(0);

#pragma unroll 1
  for (int kt = 0; kt < KT2; ++kt) {
    const int bufc = kt & 1;
    const char* Ab = ldsFlat + bufc * 32768;
    const char* Bb = ldsFlat + 65536 + bufc * 32768;
    const bool stgA = (kt + 1) < KT2;
    const bool stgB = (kt + 2) < KT2;
    bf16x8 b0[4], b1[4], a0[4], a1[4];

    // ---- Phase A: read all B + A(mf0-3) both ksubs; stage A0,A1(kt+1); 32 MFMA ----
#pragma unroll
    for (int nf = 0; nf < 4; ++nf) {
      b0[nf] = *(const bf16x8*)(Bb + rdB + nf * 2048 + cs0);
      b1[nf] = *(const bf16x8*)(Bb + rdB + nf * 2048 + (cs0 ^ 64));
    }
#pragma unroll
    for (int mf = 0; mf < 4; ++mf) {
      a0[mf] = *(const bf16x8*)(Ab + rdA + mf * 2048 + cs0);
      a1[mf] = *(const bf16x8*)(Ab + rdA + mf * 2048 + (cs0 ^ 64));
    }
    if (stgA) {
      STAGE(0, xbf, stA, bufc ^ 1, 0, kt + 1);
      STAGE(0, xbf, stA, bufc ^ 1, 1, kt + 1);
    }
    __builtin_amdgcn_s_barrier();
    asm volatile("s_waitcnt lgkmcnt(0)");
    __builtin_amdgcn_s_setprio(1);
#pragma unroll
    for (int mf = 0; mf < 4; ++mf)
#pragma unroll
      for (int nf = 0; nf < 4; ++nf)
        acc[mf][nf] = __builtin_amdgcn_mfma_f32_16x16x32_bf16(a0[mf], b0[nf], acc[mf][nf], 0, 0, 0);
#pragma unroll
    for (int mf = 0; mf < 4; ++mf)
#pragma unroll
      for (int nf = 0; nf < 4; ++nf)
        acc[mf][nf] = __builtin_amdgcn_mfma_f32_16x16x32_bf16(a1[mf], b1[nf], acc[mf][nf], 0, 0, 0);
    __builtin_amdgcn_s_setprio(0);
    __builtin_amdgcn_s_barrier();

    // ---- Phase B: read A(mf4-7) both ksubs; stage B0,B1(kt+2); 32 MFMA; boundary ----
#pragma unroll
    for (int mf = 0; mf < 4; ++mf) {
      a0[mf] = *(const bf16x8*)(Ab + rdA + (mf + 4) * 2048 + cs0);
      a1[mf] = *(const bf16x8*)(Ab + rdA + (mf + 4) * 2048 + (cs0 ^ 64));
    }
    if (stgB) {
      STAGE(1, mbf, stB, bufc, 0, kt + 2);
      STAGE(1, mbf, stB, bufc, 1, kt + 2);
    }
    __builtin_amdgcn_s_barrier();
    asm volatile("s_waitcnt lgkmcnt(0)");
    __builtin_amdgcn_s_setprio(1);
#pragma unroll
    for (int mf = 0; mf < 4; ++mf)
#pragma unroll
      for (int nf = 0; nf < 4; ++nf)
        acc[mf + 4][nf] = __builtin_amdgcn_mfma_f32_16x16x32_bf16(a0[mf], b0[nf], acc[mf + 4][nf], 0, 0, 0);
#pragma unroll
    for (int mf = 0; mf < 4; ++mf)
#pragma unroll
      for (int nf = 0; nf < 4; ++nf)
        acc[mf + 4][nf] = __builtin_amdgcn_mfma_f32_16x16x32_bf16(a1[mf], b1[nf], acc[mf + 4][nf], 0, 0, 0);
    __builtin_amdgcn_s_setprio(0);
    if (kt >= 22) {  // tail: stages skipped, counts shift -> full drain
      asm volatile("s_waitcnt vmcnt(0)");
    } else {         // steady: allow B(kt+2)'s 4 loads outstanding
      asm volatile("s_waitcnt vmcnt(4)");
    }
    __builtin_amdgcn_s_barrier();
    __builtin_amdgcn_sched_barrier(0);
  }
#undef STAGE

  // ---- epilogue: per-row min over this tile's 256 cols -> global atomicMin ----
  float m2v[4];
#pragma unroll
  for (int nf = 0; nf < 4; ++nf) m2v[nf] = m2[nBase + wn * 64 + nf * 16 + r16];
#pragma unroll
  for (int mf = 0; mf < 8; ++mf) {
    float mn[4];
#pragma unroll
    for (int i = 0; i < 4; ++i) {
      float v = m2v[0] - 2.f * acc[mf][0][i];
      v = fminf(v, m2v[1] - 2.f * acc[mf][1][i]);
      v = fminf(v, m2v[2] - 2.f * acc[mf][2][i]);
      v = fminf(v, m2v[3] - 2.f * acc[mf][3][i]);
      mn[i] = v;
    }
#pragma unroll
    for (int msk = 1; msk < 16; msk <<= 1)
#pragma unroll
      for (int i = 0; i < 4; ++i) mn[i] = fminf(mn[i], __shfl_xor(mn[i], msk));
    if (r16 == 0)
#pragma unroll
      for (int i = 0; i < 4; ++i)
        ldsMin[wn][wm * 128 + mf * 16 + g * 4 + i] = mn[i];
  }
  __syncthreads();
  if (tid < 256) {
    float v = fminf(fminf(ldsMin[0][tid], ldsMin[1][tid]),
                    fminf(ldsMin[2][tid], ldsMin[3][tid]));
    atomicMin(&closest_enc[mBase + tid], fenc(v));
  }
}

// ---------------- K3: per image, closest = x2 + decoded min; wave-parallel top-4 ----------------
__global__ void topcand_kernel(const unsigned* __restrict__ closest_enc,
                               const float* __restrict__ x2,
                               int* __restrict__ cand) {
  const int b = blockIdx.x;
  const int t = threadIdx.x;
  __shared__ float cls[P_];
  for (int p = t; p < P_; p += 256) {
    const int row = b * P_ + p;
    cls[p] = x2[row] + fdec(closest_enc[row]);
  }
  __syncthreads();
  __shared__ float wv[4];
  __shared__ int wi_[4];
  __shared__ int picked[NC_];
  for (int r = 0; r < NC_; ++r) {
    float mv = -3e38f; int mi = 1 << 30;
    for (int p = t; p < P_; p += 256) {
      bool skip = false;
      for (int c = 0; c < r; ++c) skip |= (picked[c] == p);
      float v = cls[p];
      if (!skip && (v > mv || (v == mv && p < mi))) { mv = v; mi = p; }
    }
#pragma unroll
    for (int m = 32; m >= 1; m >>= 1) {
      float ov = __shfl_xor(mv, m); int oi = __shfl_xor(mi, m);
      if (ov > mv || (ov == mv && oi < mi)) { mv = ov; mi = oi; }
    }
    if ((t & 63) == 0) { wv[t >> 6] = mv; wi_[t >> 6] = mi; }
    __syncthreads();
    if (t == 0) {
      float bv = wv[0]; int bi = wi_[0];
      for (int w = 1; w < 4; ++w)
        if (wv[w] > bv || (wv[w] == bv && wi_[w] < bi)) { bv = wv[w]; bi = wi_[w]; }
      picked[r] = bi;
      cand[b * NC_ + r] = bi;
    }
    __syncthreads();
  }
}

__device__ __forceinline__ void ins9(float* t, float v) {
  if (v < t[8]) {
    int p = 8;
    while (p > 0 && t[p - 1] > v) { t[p] = t[p - 1]; --p; }
    t[p] = v;
  }
}

// ---------------- K4: exact fp32 distances, ONE pass over memory + per-block top-9 ----------------
// 625 blocks x 4 waves; wave owns 8 rows (2 batches of 4, registers); 32 candidates each.
// 20000 = 625*32 exactly -> no bounds checks. Distances -> LDS[32][32]; 8 lanes/wave
// insertion-scan one candidate's 32 values -> ctop[bc][blk][9].
__global__ __launch_bounds__(256) void cand_dist9(
    const float* __restrict__ x, const float* __restrict__ mem,
    const float* __restrict__ x2, const float* __restrict__ m2,
    const int* __restrict__ cand, float* __restrict__ ctop) {
  const int wid = threadIdx.x >> 6, lane = threadIdx.x & 63;
  const int blk = blockIdx.x;
  __shared__ float ldsD[32][36];  // [cand][row-in-block], padded

  for (int batch = 0; batch < 2; ++batch) {
    const int rbase = blk * 32 + wid * 8 + batch * 4;
    float4 m4[4][6];
    float m2r[4];
#pragma unroll
    for (int k = 0; k < 4; ++k) {
      const float4* mrow = (const float4*)(mem + (size_t)(rbase + k) * D_);
#pragma unroll
      for (int j = 0; j < 6; ++j) m4[k][j] = mrow[j * 64 + lane];
      m2r[k] = m2[rbase + k];
    }
    for (int bc = 0; bc < B_ * NC_; ++bc) {
      const int b = bc >> 2;
      const int p = cand[bc];
      const float4* xp = (const float4*)(x + ((size_t)b * P_ + p) * D_);
      float s0 = 0.f, s1 = 0.f, s2 = 0.f, s3 = 0.f;
#pragma unroll
      for (int j = 0; j < 6; ++j) {
        float4 a = xp[j * 64 + lane];
        s0 += a.x * m4[0][j].x + a.y * m4[0][j].y + a.z * m4[0][j].z + a.w * m4[0][j].w;
        s1 += a.x * m4[1][j].x + a.y * m4[1][j].y + a.z * m4[1][j].z + a.w * m4[1][j].w;
        s2 += a.x * m4[2][j].x + a.y * m4[2][j].y + a.z * m4[2][j].z + a.w * m4[2][j].w;
        s3 += a.x * m4[3][j].x + a.y * m4[3][j].y + a.z * m4[3][j].z + a.w * m4[3][j].w;
      }
#pragma unroll
      for (int msk = 32; msk >= 1; msk >>= 1) {
        s0 += __shfl_xor(s0, msk); s1 += __shfl_xor(s1, msk);
        s2 += __shfl_xor(s2, msk); s3 += __shfl_xor(s3, msk);
      }
      if (lane == 0) {
        const float xx = x2[b * P_ + p];
        const int rloc = wid * 8 + batch * 4;
        ldsD[bc][rloc + 0] = xx + m2r[0] - 2.f * s0;
        ldsD[bc][rloc + 1] = xx + m2r[1] - 2.f * s1;
        ldsD[bc][rloc + 2] = xx + m2r[2] - 2.f * s2;
        ldsD[bc][rloc + 3] = xx + m2r[3] - 2.f * s3;
      }
    }
  }
  __syncthreads();
  if (lane < 8) {
    const int bc = wid * 8 + lane;
    float t[9];
#pragma unroll
    for (int i = 0; i < 9; ++i) t[i] = 3e38f;
    for (int i = 0; i < 32; ++i) ins9(t, ldsD[bc][i]);
    float* o = ctop + ((size_t)bc * NBLK + blk) * 9;
#pragma unroll
    for (int i = 0; i < 9; ++i) o[i] = t[i];
  }
}

// ---------------- K5: merge per-block top-9 partials -> exact top-9 per candidate ----------------
__global__ void merge_top9(const float* __restrict__ ctop, float* __restrict__ top9) {
  const int bc = blockIdx.x;  // 0..31
  const float* d = ctop + (size_t)bc * (NBLK * 9);
  float t[9];
#pragma unroll
  for (int i = 0; i < 9; ++i) t[i] = 3e38f;
  for (int n = threadIdx.x; n < NBLK * 9; n += 256) ins9(t, d[n]);
  __shared__ float l9[256 * 9];
  __shared__ float l9b[32 * 9];
  for (int i = 0; i < 9; ++i) l9[threadIdx.x * 9 + i] = t[i];
  __syncthreads();
  if (threadIdx.x < 32) {
    float u[9];
#pragma unroll
    for (int i = 0; i < 9; ++i) u[i] = 3e38f;
    for (int s = 0; s < 8; ++s)
      for (int i = 0; i < 9; ++i) ins9(u, l9[(threadIdx.x * 8 + s) * 9 + i]);
    for (int i = 0; i < 9; ++i) l9b[threadIdx.x * 9 + i] = u[i];
  }
  __syncthreads();
  if (threadIdx.x == 0) {
    float u[9];
#pragma unroll
    for (int i = 0; i < 9; ++i) u[i] = 3e38f;
    for (int s = 0; s < 32; ++s)
      for (int i = 0; i < 9; ++i) ins9(u, l9b[s * 9 + i]);
    for (int i = 0; i < 9; ++i) top9[bc * 9 + i] = u[i];
  }
}

// ---------------- K6: pick exact argmax candidate, compute score ----------------
__global__ void score_kernel(const float* __restrict__ top9, const int* __restrict__ cand,
                             float* __restrict__ out) {
  const int b = threadIdx.x;
  if (b >= B_) return;
  float bestv = -3e38f; int bestc = 0, bestp = 1 << 30;
  for (int c = 0; c < NC_; ++c) {
    float v = top9[(b * NC_ + c) * 9 + 0];
    int p = cand[b * NC_ + c];
    if (v > bestv || (v == bestv && p < bestp)) { bestv = v; bestc = c; bestp = p; }
  }
  const float* v9 = &top9[(b * NC_ + bestc) * 9];
  float mx = v9[8];  // sorted ascending
  float sum = 0.f, mxe = 0.f;
  for (int i = 0; i < 9; ++i) {
    float e = expf(v9[i] - mx);
    sum += e;
    if (e > mxe) mxe = e;
  }
  out[b] = (1.f - mxe / sum) * bestv;
}

// ---------------- launch ----------------
extern "C" void kernel_launch(void* const* d_in, const int* in_sizes, int n_in,
                              void* d_out, int out_size, void* d_ws, size_t ws_size,
                              hipStream_t stream) {
  const float* x = (const float*)d_in[0];
  const float* mem = (const float*)d_in[1];
  float* out = (float*)d_out;
  char* ws = (char*)d_ws;

  // ws layout (~82.6 MB)
  unsigned short* xbf  = (unsigned short*)(ws);                 // 19,660,800
  unsigned short* mbf  = (unsigned short*)(ws + 19660800);      // 62,128,128
  float* x2            = (float*)(ws + 81788928);               // 25,600
  float* m2            = (float*)(ws + 81814528);               // 80,896
  unsigned* closest_enc= (unsigned*)(ws + 81895424);            // 25,600
  int*   cand          = (int*)  (ws + 81921024);               // 128
  float* ctop          = (float*)(ws + 81921152);               // 720,000
  float* top9          = (float*)(ws + 82641152);               // 1,152

  hipMemsetAsync(closest_enc, 0xFF, MPAD * 4, stream);
  convert_all<<<NPAD2 + MPAD, 256, 0, stream>>>(x, mem, xbf, mbf, x2, m2);
  gemm_min8<<<MT2 * NT2, 512, 0, stream>>>(xbf, mbf, m2, closest_enc);
  topcand_kernel<<<B_, 256, 0, stream>>>(closest_enc, x2, cand);
  cand_dist9<<<NBLK, 256, 0, stream>>>(x, mem, x2, m2, cand, ctop);
  merge_top9<<<B_ * NC_, 256, 0, stream>>>(ctop, top9);
  score_kernel<<<1, 64, 0, stream>>>(top9, cand, out);
}

// Round 8
// 494.522 us; speedup vs baseline: 1.6714x; 1.1152x over previous
//
#include <hip/hip_runtime.h>
#include <hip/hip_fp8.h>
#include <math.h>

// Problem constants (reference: B,P,D,N,K = 8,784,1536,20000,9)
#define B_    8
#define P_    784
#define M_    6272      // B*P
#define D_    1536
#define N_    20000
#define NC_   8         // candidate patches per image (fp8 ranking noise -> wider net)

// 256x256 fp8 GEMM geometry (BK = 128 fp8 = one MFMA K-step)
#define MPAD  6400      // 25*256
#define NPAD2 20224     // 79*256
#define MT2   25
#define NT2   79
#define KT2   12        // 1536/128 K-tiles

#define NBLK  625       // cand-dist blocks of 32 rows (625*32 = 20000 exactly)

using i32x8  = __attribute__((ext_vector_type(8))) int;
using f32x4v = __attribute__((ext_vector_type(4))) float;

#define GLD_LDS16(src, dst)                                            \
  __builtin_amdgcn_global_load_lds(                                    \
      (__attribute__((address_space(1))) const void*)(src),            \
      (__attribute__((address_space(3))) void*)(dst), 16, 0, 0)

__device__ __forceinline__ unsigned char f2fp8(float v) {
  __hip_fp8_e4m3 q(v);            // OCP e4m3fn on gfx950
  return (unsigned char)q.__x;
}

// order-preserving float<->uint for atomicMin (all finite values)
__device__ __forceinline__ unsigned fenc(float f) {
  unsigned u = __float_as_uint(f);
  return (u >> 31) ? ~u : (u | 0x80000000u);
}
__device__ __forceinline__ float fdec(unsigned k) {
  return (k >> 31) ? __uint_as_float(k & 0x7FFFFFFFu) : __uint_as_float(~k);
}

// ---------------- K1: fused fp32 -> fp8 + row sum-of-squares for BOTH matrices ----------------
__device__ __forceinline__ void convert_one(const float* __restrict__ src,
                                            unsigned char* __restrict__ dst,
                                            float* __restrict__ sq,
                                            int row, int realrows) {
  const int t = threadIdx.x;
  if (row >= realrows) {
    unsigned* w = (unsigned*)(dst + (size_t)row * D_);
    for (int i = t; i < D_ / 4; i += 256) w[i] = 0u;   // fp8 zero
    if (t == 0) sq[row] = 1e30f;
    return;
  }
  const float4* r4 = (const float4*)(src + (size_t)row * D_);
  unsigned* w = (unsigned*)(dst + (size_t)row * D_);
  float s = 0.f;
  for (int i = t; i < D_ / 4; i += 256) {
    float4 v = r4[i];
    s += v.x * v.x + v.y * v.y + v.z * v.z + v.w * v.w;
    unsigned pk = (unsigned)f2fp8(v.x) | ((unsigned)f2fp8(v.y) << 8) |
                  ((unsigned)f2fp8(v.z) << 16) | ((unsigned)f2fp8(v.w) << 24);
    w[i] = pk;
  }
#pragma unroll
  for (int m = 32; m >= 1; m >>= 1) s += __shfl_xor(s, m);
  __shared__ float ws4[4];
  if ((t & 63) == 0) ws4[t >> 6] = s;
  __syncthreads();
  if (t == 0) sq[row] = ws4[0] + ws4[1] + ws4[2] + ws4[3];
}

__global__ void convert_all(const float* __restrict__ x, const float* __restrict__ mem,
                            unsigned char* __restrict__ xq, unsigned char* __restrict__ mq,
                            float* __restrict__ x2, float* __restrict__ m2) {
  const int blk = blockIdx.x;
  if (blk < NPAD2) convert_one(mem, mq, m2, blk, N_);
  else convert_one(x, xq, x2, blk - NPAD2, M_);
}

// ---------------- K2: 256x256 fp8 MX-MFMA GEMM (identity scales), epilogue -> atomicMin -------
// Byte-identical LDS layout/swizzle/staging to the verified bf16 kernel (rows are 128 B,
// now 128 fp8 instead of 64 bf16). K-tiles 12; per K-tile: phase A = mf0-3 (16 MFMA K=128),
// phase B = mf4-7. Fragments 32 B/lane = 2x ds_read_b128, k-chunk (lane>>4)*32 consecutive.
// C/D layout is shape-determined (== 16x16x32 bf16) -> epilogue unchanged.
__global__ __launch_bounds__(512, 2) void gemm_min8(
    const unsigned char* __restrict__ xq, const unsigned char* __restrict__ mq,
    const float* __restrict__ m2, unsigned* __restrict__ closest_enc) {
  __shared__ __attribute__((aligned(16))) char ldsFlat[131072];
  __shared__ float ldsMin[4][256];

  // --- block swizzle: bijective XCD chunking + 5-mTile supertiles ---
  const int NWG = MT2 * NT2;              // 1975
  const int bid = blockIdx.x;
  const int q = NWG >> 3, r = NWG & 7;    // 246, 7
  const int xcd = bid & 7, loc = bid >> 3;
  const int wg = (xcd < r ? xcd * (q + 1) : r * (q + 1) + (xcd - r) * q) + loc;
  const int s = wg / (5 * NT2);
  const int r2 = wg - s * (5 * NT2);
  const int mT = s * 5 + (r2 % 5);
  const int nT = r2 / 5;

  const int tid = threadIdx.x;
  const int lane = tid & 63, wid = tid >> 6;
  const int wm = wid >> 2, wn = wid & 3;      // 2 x 4 wave grid
  const int g = lane >> 4, r16 = lane & 15;
  const int mBase = mT * 256, nBase = nT * 256;

  const int stRow = wid * 8 + (lane >> 3);
  const int stA = mBase + stRow;
  const int stB = nBase + stRow;
  const int cswz16 = ((lane & 7) ^ ((lane >> 3) & 7)) * 16;  // inverse-swizzled byte col

  // reader: row byte-offset row*128; k-chunk (g*32) swizzled by ((r16&7)<<4)
  const int csl = (g * 32) ^ ((r16 & 7) << 4);
  const int csh = csl ^ 16;                       // (g*32+16)^swz, since bit4 of g*32 == 0
  const int rdA = wm * 16384 + r16 * 128;         // + mf*2048 (+ buf*32768)
  const int rdB = wn * 8192 + r16 * 128;          // + nf*2048 (+ 65536 + buf*32768)

#define STAGE(matsel, srcp, rowb, bufb, h, ktv) do {                        \
    char* dst_ = ldsFlat + (matsel) * 65536 + (bufb) * 32768 +              \
                 (h) * 16384 + wid * 1024;                                  \
    const unsigned char* s_ =                                               \
        (srcp) + (size_t)((rowb) + (h) * 128) * 1536 + (ktv) * 128 + cswz16;\
    GLD_LDS16(s_, dst_);                                                    \
    GLD_LDS16(s_ + 64 * 1536, dst_ + 8192);                                 \
  } while (0)

#define LDFRAG(base, off) ({                                                \
    int4 lo_ = *(const int4*)((base) + (off) + csl);                        \
    int4 hi_ = *(const int4*)((base) + (off) + csh);                        \
    i32x8{lo_.x, lo_.y, lo_.z, lo_.w, hi_.x, hi_.y, hi_.z, hi_.w}; })

#define MFMA8(a, b, c) __builtin_amdgcn_mfma_scale_f32_16x16x128_f8f6f4(    \
    (a), (b), (c), 0, 0, 0, 0x7F7F7F7F, 0, 0x7F7F7F7F)

  f32x4v acc[8][4];
#pragma unroll
  for (int i = 0; i < 8; ++i)
#pragma unroll
    for (int j = 0; j < 4; ++j) acc[i][j] = f32x4v{0.f, 0.f, 0.f, 0.f};

  // ---- prologue: B(0), A(0), B(1); wait first 8 of 12 loads ----
  STAGE(1, mq, stB, 0, 0, 0);
  STAGE(1, mq, stB, 0, 1, 0);
  STAGE(0, xq, stA, 0, 0, 0);
  STAGE(0, xq, stA, 0, 1, 0);
  STAGE(1, mq, stB, 1, 0, 1);
  STAGE(1, mq, stB, 1, 1, 1);
  asm volatile("s_waitcnt vmcnt(4)");
  __builtin_amdgcn_s_barrier();
  __builtin_amdgcn_sched_barrier(0);

#pragma unroll 1
  for (int kt = 0; kt < KT2; ++kt) {
    const int bufc = kt & 1;
    const char* Ab = ldsFlat + bufc * 32768;
    const char* Bb = ldsFlat + 65536 + bufc * 32768;
    const bool stgA = (kt + 1) < KT2;
    const bool stgB = (kt + 2) < KT2;
    i32x8 bf[4], af[4];

    // ---- Phase A: read all B + A(mf0-3); stage A(kt+1); 16 MFMA ----
#pragma unroll
    for (int nf = 0; nf < 4; ++nf) bf[nf] = LDFRAG(Bb, rdB + nf * 2048);
#pragma unroll
    for (int mf = 0; mf < 4; ++mf) af[mf] = LDFRAG(Ab, rdA + mf * 2048);
    if (stgA) {
      STAGE(0, xq, stA, bufc ^ 1, 0, kt + 1);
      STAGE(0, xq, stA, bufc ^ 1, 1, kt + 1);
    }
    __builtin_amdgcn_s_barrier();
    asm volatile("s_waitcnt lgkmcnt(0)");
    __builtin_amdgcn_s_setprio(1);
#pragma unroll
    for (int mf = 0; mf < 4; ++mf)
#pragma unroll
      for (int nf = 0; nf < 4; ++nf)
        acc[mf][nf] = MFMA8(af[mf], bf[nf], acc[mf][nf]);
    __builtin_amdgcn_s_setprio(0);
    __builtin_amdgcn_s_barrier();

    // ---- Phase B: read A(mf4-7); stage B(kt+2) -> same buf (B fully read); 16 MFMA ----
#pragma unroll
    for (int mf = 0; mf < 4; ++mf) af[mf] = LDFRAG(Ab, rdA + (mf + 4) * 2048);
    if (stgB) {
      STAGE(1, mq, stB, bufc, 0, kt + 2);
      STAGE(1, mq, stB, bufc, 1, kt + 2);
    }
    __builtin_amdgcn_s_barrier();
    asm volatile("s_waitcnt lgkmcnt(0)");
    __builtin_amdgcn_s_setprio(1);
#pragma unroll
    for (int mf = 0; mf < 4; ++mf)
#pragma unroll
      for (int nf = 0; nf < 4; ++nf)
        acc[mf + 4][nf] = MFMA8(af[mf], bf[nf], acc[mf + 4][nf]);
    __builtin_amdgcn_s_setprio(0);
    if (kt >= KT2 - 2) {  // tail: stages skipped, counts shift -> full drain
      asm volatile("s_waitcnt vmcnt(0)");
    } else {              // steady: allow B(kt+2)'s 4 loads outstanding
      asm volatile("s_waitcnt vmcnt(4)");
    }
    __builtin_amdgcn_s_barrier();
    __builtin_amdgcn_sched_barrier(0);
  }
#undef STAGE
#undef LDFRAG
#undef MFMA8

  // ---- epilogue: per-row min over this tile's 256 cols -> global atomicMin ----
  // C/D layout: col = nBase + wn*64 + nf*16 + (lane&15), row = wm*128 + mf*16 + (lane>>4)*4 + i
  float m2v[4];
#pragma unroll
  for (int nf = 0; nf < 4; ++nf) m2v[nf] = m2[nBase + wn * 64 + nf * 16 + r16];
#pragma unroll
  for (int mf = 0; mf < 8; ++mf) {
    float mn[4];
#pragma unroll
    for (int i = 0; i < 4; ++i) {
      float v = m2v[0] - 2.f * acc[mf][0][i];
      v = fminf(v, m2v[1] - 2.f * acc[mf][1][i]);
      v = fminf(v, m2v[2] - 2.f * acc[mf][2][i]);
      v = fminf(v, m2v[3] - 2.f * acc[mf][3][i]);
      mn[i] = v;
    }
#pragma unroll
    for (int msk = 1; msk < 16; msk <<= 1)
#pragma unroll
      for (int i = 0; i < 4; ++i) mn[i] = fminf(mn[i], __shfl_xor(mn[i], msk));
    if (r16 == 0)
#pragma unroll
      for (int i = 0; i < 4; ++i)
        ldsMin[wn][wm * 128 + mf * 16 + g * 4 + i] = mn[i];
  }
  __syncthreads();
  if (tid < 256) {
    float v = fminf(fminf(ldsMin[0][tid], ldsMin[1][tid]),
                    fminf(ldsMin[2][tid], ldsMin[3][tid]));
    atomicMin(&closest_enc[mBase + tid], fenc(v));
  }
}

// ---------------- K3: per image, closest = x2 + decoded min; wave-parallel top-NC ----------------
__global__ void topcand_kernel(const unsigned* __restrict__ closest_enc,
                               const float* __restrict__ x2,
                               int* __restrict__ cand) {
  const int b = blockIdx.x;
  const int t = threadIdx.x;
  __shared__ float cls[P_];
  for (int p = t; p < P_; p += 256) {
    const int row = b * P_ + p;
    cls[p] = x2[row] + fdec(closest_enc[row]);
  }
  __syncthreads();
  __shared__ float wv[4];
  __shared__ int wi_[4];
  __shared__ int picked[NC_];
  for (int r = 0; r < NC_; ++r) {
    float mv = -3e38f; int mi = 1 << 30;
    for (int p = t; p < P_; p += 256) {
      bool skip = false;
      for (int c = 0; c < r; ++c) skip |= (picked[c] == p);
      float v = cls[p];
      if (!skip && (v > mv || (v == mv && p < mi))) { mv = v; mi = p; }
    }
#pragma unroll
    for (int m = 32; m >= 1; m >>= 1) {
      float ov = __shfl_xor(mv, m); int oi = __shfl_xor(mi, m);
      if (ov > mv || (ov == mv && oi < mi)) { mv = ov; mi = oi; }
    }
    if ((t & 63) == 0) { wv[t >> 6] = mv; wi_[t >> 6] = mi; }
    __syncthreads();
    if (t == 0) {
      float bv = wv[0]; int bi = wi_[0];
      for (int w = 1; w < 4; ++w)
        if (wv[w] > bv || (wv[w] == bv && wi_[w] < bi)) { bv = wv[w]; bi = wi_[w]; }
      picked[r] = bi;
      cand[b * NC_ + r] = bi;
    }
    __syncthreads();
  }
}

__device__ __forceinline__ void ins9(float* t, float v) {
  if (v < t[8]) {
    int p = 8;
    while (p > 0 && t[p - 1] > v) { t[p] = t[p - 1]; --p; }
    t[p] = v;
  }
}

// ---------------- K4: exact fp32 distances, ONE pass over memory + per-block top-9 ----------------
// 625 blocks x 4 waves; wave owns 8 rows (2 batches of 4, registers); 64 (image,cand) pairs.
__global__ __launch_bounds__(256) void cand_dist9(
    const float* __restrict__ x, const float* __restrict__ mem,
    const float* __restrict__ x2, const float* __restrict__ m2,
    const int* __restrict__ cand, float* __restrict__ ctop) {
  const int wid = threadIdx.x >> 6, lane = threadIdx.x & 63;
  const int blk = blockIdx.x;
  __shared__ float ldsD[B_ * NC_][36];  // [cand][row-in-block], padded

  for (int batch = 0; batch < 2; ++batch) {
    const int rbase = blk * 32 + wid * 8 + batch * 4;
    float4 m4[4][6];
    float m2r[4];
#pragma unroll
    for (int k = 0; k < 4; ++k) {
      const float4* mrow = (const float4*)(mem + (size_t)(rbase + k) * D_);
#pragma unroll
      for (int j = 0; j < 6; ++j) m4[k][j] = mrow[j * 64 + lane];
      m2r[k] = m2[rbase + k];
    }
    for (int bc = 0; bc < B_ * NC_; ++bc) {
      const int b = bc / NC_;
      const int p = cand[bc];
      const float4* xp = (const float4*)(x + ((size_t)b * P_ + p) * D_);
      float s0 = 0.f, s1 = 0.f, s2 = 0.f, s3 = 0.f;
#pragma unroll
      for (int j = 0; j < 6; ++j) {
        float4 a = xp[j * 64 + lane];
        s0 += a.x * m4[0][j].x + a.y * m4[0][j].y + a.z * m4[0][j].z + a.w * m4[0][j].w;
        s1 += a.x * m4[1][j].x + a.y * m4[1][j].y + a.z * m4[1][j].z + a.w * m4[1][j].w;
        s2 += a.x * m4[2][j].x + a.y * m4[2][j].y + a.z * m4[2][j].z + a.w * m4[2][j].w;
        s3 += a.x * m4[3][j].x + a.y * m4[3][j].y + a.z * m4[3][j].z + a.w * m4[3][j].w;
      }
#pragma unroll
      for (int msk = 32; msk >= 1; msk >>= 1) {
        s0 += __shfl_xor(s0, msk); s1 += __shfl_xor(s1, msk);
        s2 += __shfl_xor(s2, msk); s3 += __shfl_xor(s3, msk);
      }
      if (lane == 0) {
        const float xx = x2[b * P_ + p];
        const int rloc = wid * 8 + batch * 4;
        ldsD[bc][rloc + 0] = xx + m2r[0] - 2.f * s0;
        ldsD[bc][rloc + 1] = xx + m2r[1] - 2.f * s1;
        ldsD[bc][rloc + 2] = xx + m2r[2] - 2.f * s2;
        ldsD[bc][rloc + 3] = xx + m2r[3] - 2.f * s3;
      }
    }
  }
  __syncthreads();
  if (lane < 16) {
    const int bc = wid * 16 + lane;
    float t[9];
#pragma unroll
    for (int i = 0; i < 9; ++i) t[i] = 3e38f;
    for (int i = 0; i < 32; ++i) ins9(t, ldsD[bc][i]);
    float* o = ctop + ((size_t)bc * NBLK + blk) * 9;
#pragma unroll
    for (int i = 0; i < 9; ++i) o[i] = t[i];
  }
}

// ---------------- K5: merge per-block top-9 partials -> exact top-9 per candidate ----------------
__global__ void merge_top9(const float* __restrict__ ctop, float* __restrict__ top9) {
  const int bc = blockIdx.x;  // 0..63
  const float* d = ctop + (size_t)bc * (NBLK * 9);
  float t[9];
#pragma unroll
  for (int i = 0; i < 9; ++i) t[i] = 3e38f;
  for (int n = threadIdx.x; n < NBLK * 9; n += 256) ins9(t, d[n]);
  __shared__ float l9[256 * 9];
  __shared__ float l9b[32 * 9];
  for (int i = 0; i < 9; ++i) l9[threadIdx.x * 9 + i] = t[i];
  __syncthreads();
  if (threadIdx.x < 32) {
    float u[9];
#pragma unroll
    for (int i = 0; i < 9; ++i) u[i] = 3e38f;
    for (int s = 0; s < 8; ++s)
      for (int i = 0; i < 9; ++i) ins9(u, l9[(threadIdx.x * 8 + s) * 9 + i]);
    for (int i = 0; i < 9; ++i) l9b[threadIdx.x * 9 + i] = u[i];
  }
  __syncthreads();
  if (threadIdx.x == 0) {
    float u[9];
#pragma unroll
    for (int i = 0; i < 9; ++i) u[i] = 3e38f;
    for (int s = 0; s < 32; ++s)
      for (int i = 0; i < 9; ++i) ins9(u, l9b[s * 9 + i]);
    for (int i = 0; i < 9; ++i) top9[bc * 9 + i] = u[i];
  }
}

// ---------------- K6: pick exact argmax candidate, compute score ----------------
__global__ void score_kernel(const float* __restrict__ top9, const int* __restrict__ cand,
                             float* __restrict__ out) {
  const int b = threadIdx.x;
  if (b >= B_) return;
  float bestv = -3e38f; int bestc = 0, bestp = 1 << 30;
  for (int c = 0; c < NC_; ++c) {
    float v = top9[(b * NC_ + c) * 9 + 0];
    int p = cand[b * NC_ + c];
    if (v > bestv || (v == bestv && p < bestp)) { bestv = v; bestc = c; bestp = p; }
  }
  const float* v9 = &top9[(b * NC_ + bestc) * 9];
  float mx = v9[8];  // sorted ascending
  float sum = 0.f, mxe = 0.f;
  for (int i = 0; i < 9; ++i) {
    float e = expf(v9[i] - mx);
    sum += e;
    if (e > mxe) mxe = e;
  }
  out[b] = (1.f - mxe / sum) * bestv;
}

// ---------------- launch ----------------
extern "C" void kernel_launch(void* const* d_in, const int* in_sizes, int n_in,
                              void* d_out, int out_size, void* d_ws, size_t ws_size,
                              hipStream_t stream) {
  const float* x = (const float*)d_in[0];
  const float* mem = (const float*)d_in[1];
  float* out = (float*)d_out;
  char* ws = (char*)d_ws;

  // ws layout (~42.5 MB)
  unsigned char* xq    = (unsigned char*)(ws);                  //  9,830,400
  unsigned char* mq    = (unsigned char*)(ws + 9830400);        // 31,064,064
  float* x2            = (float*)(ws + 40894464);               // 25,600
  float* m2            = (float*)(ws + 40920064);               // 80,896
  unsigned* closest_enc= (unsigned*)(ws + 41000960);            // 25,600
  int*   cand          = (int*)  (ws + 41026560);               // 256
  float* ctop          = (float*)(ws + 41026816);               // 1,440,000
  float* top9          = (float*)(ws + 42466816);               // 2,304

  hipMemsetAsync(closest_enc, 0xFF, MPAD * 4, stream);
  convert_all<<<NPAD2 + MPAD, 256, 0, stream>>>(x, mem, xq, mq, x2, m2);
  gemm_min8<<<MT2 * NT2, 512, 0, stream>>>(xq, mq, m2, closest_enc);
  topcand_kernel<<<B_, 256, 0, stream>>>(closest_enc, x2, cand);
  cand_dist9<<<NBLK, 256, 0, stream>>>(x, mem, x2, m2, cand, ctop);
  merge_top9<<<B_ * NC_, 256, 0, stream>>>(ctop, top9);
  score_kernel<<<1, 64, 0, stream>>>(top9, cand, out);
}